// Round 2
// baseline (1465.199 us; speedup 1.0000x reference)
//
#include <hip/hip_runtime.h>
#include <hip/hip_bf16.h>
#include <math.h>

#define NN 50000
#define IN_F 128
#define DD 64
#define HH 4
#define CC 10
#define GG 64
#define NEG_SLOPE 0.2f

// ---------------- CSR build ----------------
__global__ void hist_kernel(const int* __restrict__ dst, int E, int* __restrict__ counts) {
    int i = blockIdx.x * blockDim.x + threadIdx.x;
    if (i < E) atomicAdd(&counts[dst[i]], 1);
}

__global__ __launch_bounds__(1024) void scan_kernel(const int* __restrict__ counts,
                                                    int* __restrict__ row_ptr,
                                                    int* __restrict__ fill,
                                                    int n, int E) {
    __shared__ int sums[1024];
    int t = threadIdx.x;
    int chunk = (n + 1023) / 1024;
    int lo = t * chunk;
    int hi = min(lo + chunk, n);
    int s = 0;
    for (int i = lo; i < hi; ++i) s += counts[i];
    sums[t] = s;
    __syncthreads();
    for (int o = 1; o < 1024; o <<= 1) {
        int u = (t >= o) ? sums[t - o] : 0;
        __syncthreads();
        sums[t] += u;
        __syncthreads();
    }
    int base = sums[t] - s;  // exclusive prefix
    for (int i = lo; i < hi; ++i) {
        int c = counts[i];
        row_ptr[i] = base;
        fill[i] = base;
        base += c;
    }
    if (t == 0) row_ptr[n] = E;
}

__global__ void scatter_kernel(const int* __restrict__ src, const int* __restrict__ dst,
                               int E, int* __restrict__ fill, int* __restrict__ col_src) {
    int i = blockIdx.x * blockDim.x + threadIdx.x;
    if (i < E) {
        int p = atomicAdd(&fill[dst[i]], 1);
        col_src[p] = src[i];
    }
}

// ---------------- GEMM (fp32, 64x64x32 tiles) + fused el/er epilogue ----------------
// grid.y = head index (Ncols = H*64, each block-column is exactly one head).
__global__ __launch_bounds__(256) void gemm_f32_eler(const float* __restrict__ A,
                                                     const float* __restrict__ B,
                                                     float* __restrict__ C,
                                                     const float* __restrict__ al,
                                                     const float* __restrict__ ar,
                                                     float* __restrict__ el,
                                                     float* __restrict__ er,
                                                     int M, int Ncols, int K, int H) {
    __shared__ float As[32][68];  // As[k][m] (transposed), padded
    __shared__ float Bs[32][68];  // Bs[k][n]
    const int bm = blockIdx.x * 64;
    const int bn = blockIdx.y * 64;
    const int h = blockIdx.y;     // head index
    const int t = threadIdx.x;
    const int tx = t & 15, ty = t >> 4;
    const int ar_ = t >> 3;        // 0..31 (row within A tile)
    const int ac = (t & 7) * 4;    // k offset
    const int bkr = t >> 4;        // 0..15 (k row within B tile)
    const int bc = (t & 15) * 4;   // n offset
    float acc[4][4] = {};
    for (int k0 = 0; k0 < K; k0 += 32) {
#pragma unroll
        for (int p = 0; p < 2; ++p) {
            int row = bm + ar_ + p * 32;
            float4 v = make_float4(0.f, 0.f, 0.f, 0.f);
            if (row < M) v = *(const float4*)&A[(size_t)row * K + k0 + ac];
            As[ac + 0][ar_ + p * 32] = v.x;
            As[ac + 1][ar_ + p * 32] = v.y;
            As[ac + 2][ar_ + p * 32] = v.z;
            As[ac + 3][ar_ + p * 32] = v.w;
        }
#pragma unroll
        for (int p = 0; p < 2; ++p) {
            int krow = k0 + bkr + p * 16;
            float4 v = *(const float4*)&B[(size_t)krow * Ncols + bn + bc];
            *(float4*)&Bs[bkr + p * 16][bc] = v;
        }
        __syncthreads();
#pragma unroll
        for (int kk = 0; kk < 32; ++kk) {
            float4 a = *(const float4*)&As[kk][ty * 4];
            float4 b = *(const float4*)&Bs[kk][tx * 4];
            acc[0][0] += a.x * b.x; acc[0][1] += a.x * b.y; acc[0][2] += a.x * b.z; acc[0][3] += a.x * b.w;
            acc[1][0] += a.y * b.x; acc[1][1] += a.y * b.y; acc[1][2] += a.y * b.z; acc[1][3] += a.y * b.w;
            acc[2][0] += a.z * b.x; acc[2][1] += a.z * b.y; acc[2][2] += a.z * b.z; acc[2][3] += a.z * b.w;
            acc[3][0] += a.w * b.x; acc[3][1] += a.w * b.y; acc[3][2] += a.w * b.z; acc[3][3] += a.w * b.w;
        }
        __syncthreads();
    }
    // C write
#pragma unroll
    for (int i = 0; i < 4; ++i) {
        int row = bm + ty * 4 + i;
        if (row < M) {
            float4 v = make_float4(acc[i][0], acc[i][1], acc[i][2], acc[i][3]);
            *(float4*)&C[(size_t)row * Ncols + bn + tx * 4] = v;
        }
    }
    // fused el/er: el[row,h] = sum_d z[row,h,d]*al[h,d]; this block owns head h, cols tx*4..tx*4+3
    float* redl = (float*)As;  // 64 rows x 16 partials
    float* redr = (float*)Bs;
#pragma unroll
    for (int i = 0; i < 4; ++i) {
        float pl = acc[i][0] * al[h * DD + tx * 4 + 0] + acc[i][1] * al[h * DD + tx * 4 + 1] +
                   acc[i][2] * al[h * DD + tx * 4 + 2] + acc[i][3] * al[h * DD + tx * 4 + 3];
        float pr = acc[i][0] * ar[h * DD + tx * 4 + 0] + acc[i][1] * ar[h * DD + tx * 4 + 1] +
                   acc[i][2] * ar[h * DD + tx * 4 + 2] + acc[i][3] * ar[h * DD + tx * 4 + 3];
        redl[(ty * 4 + i) * 16 + tx] = pl;
        redr[(ty * 4 + i) * 16 + tx] = pr;
    }
    __syncthreads();
    if (t < 64) {
        int row = bm + t;
        if (row < M) {
            float sl = 0.f, sr = 0.f;
#pragma unroll
            for (int k = 0; k < 16; ++k) {
                sl += redl[t * 16 + k];
                sr += redr[t * 16 + k];
            }
            el[(size_t)row * H + h] = sl;
            er[(size_t)row * H + h] = sr;
        }
    }
}

// ---------------- GAT aggregate: one wave per dst node, online softmax, heads-inner ----------------
template <int H>
__global__ __launch_bounds__(256) void gat_agg(const float* __restrict__ z,
                                               const float* __restrict__ el,
                                               const float* __restrict__ er,
                                               const int* __restrict__ row_ptr,
                                               const int* __restrict__ col_src,
                                               float* __restrict__ out) {
    int wave = blockIdx.x * (blockDim.x >> 6) + (threadIdx.x >> 6);
    int lane = threadIdx.x & 63;
    if (wave >= NN) return;
    int start = row_ptr[wave], end = row_ptr[wave + 1];
    float erd[H], m[H], den[H], acc[H];
#pragma unroll
    for (int h = 0; h < H; ++h) {
        erd[h] = er[(size_t)wave * H + h];
        m[h] = -1e30f;
        den[h] = 0.f;
        acc[h] = 0.f;
    }
    for (int i = start; i < end; ++i) {
        int s = col_src[i];
        const float* elp = &el[(size_t)s * H];
        const float* zp = &z[(size_t)s * H * DD + lane];
#pragma unroll
        for (int h = 0; h < H; ++h) {
            float e = elp[h] + erd[h];
            e = (e >= 0.f) ? e : NEG_SLOPE * e;
            float zv = zp[h * DD];
            if (e <= m[h]) {
                float w = __expf(e - m[h]);
                den[h] += w;
                acc[h] += w * zv;
            } else {
                float sc = __expf(m[h] - e);  // 0 on first edge (m=-1e30)
                den[h] = den[h] * sc + 1.f;
                acc[h] = acc[h] * sc + zv;
                m[h] = e;
            }
        }
    }
#pragma unroll
    for (int h = 0; h < H; ++h) {
        float r = acc[h] / den[h];
        out[(size_t)wave * H * DD + h * DD + lane] = (r > 0.f) ? r : 0.f;  // fused ReLU
    }
}

// ---------------- pooling: one block per graph (graph_id sorted) ----------------
__device__ inline int lower_bound_dev(const int* a, int n, int v) {
    int lo = 0, hi = n;
    while (lo < hi) {
        int mid = (lo + hi) >> 1;
        if (a[mid] < v) lo = mid + 1; else hi = mid;
    }
    return lo;
}

__global__ __launch_bounds__(256) void pool_kernel(const float* __restrict__ x,
                                                   const int* __restrict__ gid,
                                                   float* __restrict__ pooled,
                                                   float* __restrict__ gcnt) {
    int g = blockIdx.x;
    int start = lower_bound_dev(gid, NN, g);
    int end = lower_bound_dev(gid, NN, g + 1);
    int lane = threadIdx.x & 63;
    int w = threadIdx.x >> 6;
    float acc = 0.f;
    for (int i = start + w; i < end; i += 4) acc += x[(size_t)i * DD + lane];
    __shared__ float red[4][DD];
    red[w][lane] = acc;
    __syncthreads();
    if (w == 0) {
        float s = red[0][lane] + red[1][lane] + red[2][lane] + red[3][lane];
        pooled[g * DD + lane] = s;
        if (lane == 0) gcnt[g] = (float)(end - start);
    }
}

// ---------------- head: fc1+ELU+fc2+log_softmax(axis=0), 1 block / 64 threads ----------------
__global__ __launch_bounds__(64) void head_kernel(const float* __restrict__ pooled,
                                                  const float* __restrict__ gcnt,
                                                  const float* __restrict__ fc1w,
                                                  const float* __restrict__ fc1b,
                                                  const float* __restrict__ fc2w,
                                                  const float* __restrict__ fc2b,
                                                  float* __restrict__ out) {
    __shared__ float P[GG][DD + 1];
    __shared__ float Y1[GG][DD + 1];
    int g = threadIdx.x;  // one lane per graph
    float c = fmaxf(gcnt[g], 1.0f);
    for (int k = 0; k < DD; ++k) P[g][k] = pooled[g * DD + k] / c;
    __syncthreads();
    for (int j = 0; j < DD; ++j) {
        float s = fc1b[j];
        for (int k = 0; k < DD; ++k) s += P[g][k] * fc1w[k * DD + j];
        Y1[g][j] = (s > 0.f) ? s : expm1f(s);  // ELU alpha=1
    }
    __syncthreads();
    float y2[CC];
    for (int c2 = 0; c2 < CC; ++c2) {
        float s = fc2b[c2];
        for (int j = 0; j < DD; ++j) s += Y1[g][j] * fc2w[j * CC + c2];
        y2[c2] = s;
    }
    // log_softmax over axis 0 (across graphs = across the 64 lanes)
    for (int c2 = 0; c2 < CC; ++c2) {
        float m = y2[c2];
#pragma unroll
        for (int o = 32; o > 0; o >>= 1) m = fmaxf(m, __shfl_xor(m, o));
        float sexp = __expf(y2[c2] - m);
#pragma unroll
        for (int o = 32; o > 0; o >>= 1) sexp += __shfl_xor(sexp, o);
        out[g * CC + c2] = y2[c2] - m - logf(sexp);
    }
}

// ---------------- launcher ----------------
extern "C" void kernel_launch(void* const* d_in, const int* in_sizes, int n_in,
                              void* d_out, int out_size, void* d_ws, size_t ws_size,
                              hipStream_t stream) {
    const float* h    = (const float*)d_in[0];
    const int* src    = (const int*)d_in[1];
    const int* dst    = (const int*)d_in[2];
    const int* gid    = (const int*)d_in[3];
    const float* W0   = (const float*)d_in[4];
    const float* al0  = (const float*)d_in[5];
    const float* ar0  = (const float*)d_in[6];
    const float* W1   = (const float*)d_in[7];
    const float* al1  = (const float*)d_in[8];
    const float* ar1  = (const float*)d_in[9];
    const float* W2   = (const float*)d_in[10];
    const float* al2  = (const float*)d_in[11];
    const float* ar2  = (const float*)d_in[12];
    const float* W3   = (const float*)d_in[13];
    const float* al3  = (const float*)d_in[14];
    const float* ar3  = (const float*)d_in[15];
    const float* fc1w = (const float*)d_in[16];
    const float* fc1b = (const float*)d_in[17];
    const float* fc2w = (const float*)d_in[18];
    const float* fc2b = (const float*)d_in[19];
    const int E = in_sizes[1];

    char* wsb = (char*)d_ws;
    size_t off = 0;
    auto alloc = [&](size_t bytes) -> void* {
        void* p = wsb + off;
        off = (off + bytes + 255) & ~(size_t)255;
        return p;
    };
    float* bufA    = (float*)alloc((size_t)NN * 256 * 4);
    float* bufZ    = (float*)alloc((size_t)NN * 256 * 4);
    float* el      = (float*)alloc((size_t)NN * HH * 4);
    float* er      = (float*)alloc((size_t)NN * HH * 4);
    int*   counts  = (int*)alloc((size_t)NN * 4);
    int*   row_ptr = (int*)alloc((size_t)(NN + 1) * 4);
    int*   fill    = (int*)alloc((size_t)NN * 4);
    int*   col_src = (int*)alloc((size_t)E * 4);
    float* pooled  = (float*)alloc((size_t)GG * DD * 4);
    float* gcnt    = (float*)alloc((size_t)GG * 4);

    // ---- CSR build (same graph reused by all 4 layers) ----
    hipMemsetAsync(counts, 0, (size_t)NN * 4, stream);
    int eg = (E + 255) / 256;
    hist_kernel<<<eg, 256, 0, stream>>>(dst, E, counts);
    scan_kernel<<<1, 1024, 0, stream>>>(counts, row_ptr, fill, NN, E);
    scatter_kernel<<<eg, 256, 0, stream>>>(src, dst, E, fill, col_src);

    const int gemmGridM = (NN + 63) / 64;  // 782
    const int waveBlocks = (NN + 3) / 4;   // 12500 (4 waves/block)

    // ---- layer 0: h[N,128] @ W0 -> z[N,4,64] ----
    gemm_f32_eler<<<dim3(gemmGridM, 4), 256, 0, stream>>>(h, W0, bufZ, al0, ar0, el, er, NN, 256, IN_F, 4);
    gat_agg<4><<<waveBlocks, 256, 0, stream>>>(bufZ, el, er, row_ptr, col_src, bufA);

    // ---- layer 1 ----
    gemm_f32_eler<<<dim3(gemmGridM, 4), 256, 0, stream>>>(bufA, W1, bufZ, al1, ar1, el, er, NN, 256, 256, 4);
    gat_agg<4><<<waveBlocks, 256, 0, stream>>>(bufZ, el, er, row_ptr, col_src, bufA);

    // ---- layer 2 ----
    gemm_f32_eler<<<dim3(gemmGridM, 4), 256, 0, stream>>>(bufA, W2, bufZ, al2, ar2, el, er, NN, 256, 256, 4);
    gat_agg<4><<<waveBlocks, 256, 0, stream>>>(bufZ, el, er, row_ptr, col_src, bufA);

    // ---- layer 3 (H=1, out D=64) ----
    gemm_f32_eler<<<dim3(gemmGridM, 1), 256, 0, stream>>>(bufA, W3, bufZ, al3, ar3, el, er, NN, 64, 256, 1);
    gat_agg<1><<<waveBlocks, 256, 0, stream>>>(bufZ, el, er, row_ptr, col_src, bufA);

    // ---- pooling + head ----
    pool_kernel<<<GG, 256, 0, stream>>>(bufA, gid, pooled, gcnt);
    head_kernel<<<1, 64, 0, stream>>>(pooled, gcnt, fc1w, fc1b, fc2w, fc2b, (float*)d_out);
}

// Round 3
// 1151.477 us; speedup vs baseline: 1.2725x; 1.2725x over previous
//
#include <hip/hip_runtime.h>
#include <hip/hip_bf16.h>
#include <math.h>

#define NN 50000
#define IN_F 128
#define DD 64
#define HH 4
#define CC 10
#define GG 64
#define NEG_SLOPE 0.2f

// ---------------- wave helpers ----------------
__device__ inline float wave_max(float v) {
#pragma unroll
    for (int o = 32; o > 0; o >>= 1) v = fmaxf(v, __shfl_xor(v, o));
    return v;
}
__device__ inline float wave_sum(float v) {
#pragma unroll
    for (int o = 32; o > 0; o >>= 1) v += __shfl_xor(v, o);
    return v;
}

// ---------------- CSR build ----------------
__global__ void hist_kernel(const int* __restrict__ dst, int E, int* __restrict__ counts) {
    int i = blockIdx.x * blockDim.x + threadIdx.x;
    if (i < E) atomicAdd(&counts[dst[i]], 1);
}

__global__ __launch_bounds__(1024) void scan_kernel(const int* __restrict__ counts,
                                                    int* __restrict__ row_ptr,
                                                    int* __restrict__ fill,
                                                    int n, int E) {
    __shared__ int sums[1024];
    int t = threadIdx.x;
    int chunk = (n + 1023) / 1024;
    int lo = t * chunk;
    int hi = min(lo + chunk, n);
    int s = 0;
    for (int i = lo; i < hi; ++i) s += counts[i];
    sums[t] = s;
    __syncthreads();
    for (int o = 1; o < 1024; o <<= 1) {
        int u = (t >= o) ? sums[t - o] : 0;
        __syncthreads();
        sums[t] += u;
        __syncthreads();
    }
    int base = sums[t] - s;  // exclusive prefix
    for (int i = lo; i < hi; ++i) {
        int c = counts[i];
        row_ptr[i] = base;
        fill[i] = base;
        base += c;
    }
    if (t == 0) row_ptr[n] = E;
}

__global__ void scatter_kernel(const int* __restrict__ src, const int* __restrict__ dst,
                               int E, int* __restrict__ fill, int* __restrict__ col_src) {
    int i = blockIdx.x * blockDim.x + threadIdx.x;
    if (i < E) {
        int p = atomicAdd(&fill[dst[i]], 1);
        col_src[p] = src[i];
    }
}

// ---------------- GEMM (fp32, 64x64x32 tiles) + fused el/er epilogue ----------------
__global__ __launch_bounds__(256) void gemm_f32_eler(const float* __restrict__ A,
                                                     const float* __restrict__ B,
                                                     float* __restrict__ C,
                                                     const float* __restrict__ al,
                                                     const float* __restrict__ ar,
                                                     float* __restrict__ el,
                                                     float* __restrict__ er,
                                                     int M, int Ncols, int K, int H) {
    __shared__ float As[32][68];
    __shared__ float Bs[32][68];
    const int bm = blockIdx.x * 64;
    const int bn = blockIdx.y * 64;
    const int h = blockIdx.y;
    const int t = threadIdx.x;
    const int tx = t & 15, ty = t >> 4;
    const int ar_ = t >> 3;
    const int ac = (t & 7) * 4;
    const int bkr = t >> 4;
    const int bc = (t & 15) * 4;
    float acc[4][4] = {};
    for (int k0 = 0; k0 < K; k0 += 32) {
#pragma unroll
        for (int p = 0; p < 2; ++p) {
            int row = bm + ar_ + p * 32;
            float4 v = make_float4(0.f, 0.f, 0.f, 0.f);
            if (row < M) v = *(const float4*)&A[(size_t)row * K + k0 + ac];
            As[ac + 0][ar_ + p * 32] = v.x;
            As[ac + 1][ar_ + p * 32] = v.y;
            As[ac + 2][ar_ + p * 32] = v.z;
            As[ac + 3][ar_ + p * 32] = v.w;
        }
#pragma unroll
        for (int p = 0; p < 2; ++p) {
            int krow = k0 + bkr + p * 16;
            float4 v = *(const float4*)&B[(size_t)krow * Ncols + bn + bc];
            *(float4*)&Bs[bkr + p * 16][bc] = v;
        }
        __syncthreads();
#pragma unroll
        for (int kk = 0; kk < 32; ++kk) {
            float4 a = *(const float4*)&As[kk][ty * 4];
            float4 b = *(const float4*)&Bs[kk][tx * 4];
            acc[0][0] += a.x * b.x; acc[0][1] += a.x * b.y; acc[0][2] += a.x * b.z; acc[0][3] += a.x * b.w;
            acc[1][0] += a.y * b.x; acc[1][1] += a.y * b.y; acc[1][2] += a.y * b.z; acc[1][3] += a.y * b.w;
            acc[2][0] += a.z * b.x; acc[2][1] += a.z * b.y; acc[2][2] += a.z * b.z; acc[2][3] += a.z * b.w;
            acc[3][0] += a.w * b.x; acc[3][1] += a.w * b.y; acc[3][2] += a.w * b.z; acc[3][3] += a.w * b.w;
        }
        __syncthreads();
    }
#pragma unroll
    for (int i = 0; i < 4; ++i) {
        int row = bm + ty * 4 + i;
        if (row < M) {
            float4 v = make_float4(acc[i][0], acc[i][1], acc[i][2], acc[i][3]);
            *(float4*)&C[(size_t)row * Ncols + bn + tx * 4] = v;
        }
    }
    // fused el/er
    float* redl = (float*)As;
    float* redr = (float*)Bs;
#pragma unroll
    for (int i = 0; i < 4; ++i) {
        float pl = acc[i][0] * al[h * DD + tx * 4 + 0] + acc[i][1] * al[h * DD + tx * 4 + 1] +
                   acc[i][2] * al[h * DD + tx * 4 + 2] + acc[i][3] * al[h * DD + tx * 4 + 3];
        float pr = acc[i][0] * ar[h * DD + tx * 4 + 0] + acc[i][1] * ar[h * DD + tx * 4 + 1] +
                   acc[i][2] * ar[h * DD + tx * 4 + 2] + acc[i][3] * ar[h * DD + tx * 4 + 3];
        redl[(ty * 4 + i) * 16 + tx] = pl;
        redr[(ty * 4 + i) * 16 + tx] = pr;
    }
    __syncthreads();
    if (t < 64) {
        int row = bm + t;
        if (row < M) {
            float sl = 0.f, sr = 0.f;
#pragma unroll
            for (int k = 0; k < 16; ++k) {
                sl += redl[t * 16 + k];
                sr += redr[t * 16 + k];
            }
            el[(size_t)row * H + h] = sl;
            er[(size_t)row * H + h] = sr;
        }
    }
}

// ---------------- attention weights: one wave per dst, lane = edge ----------------
// writes exarr[i][H] = exp(e - m[dst]) (unnormalized), invden[dst][H] = 1/sum
template <int H>
__global__ __launch_bounds__(256) void attn_kernel(const float* __restrict__ el,
                                                   const float* __restrict__ er,
                                                   const int* __restrict__ row_ptr,
                                                   const int* __restrict__ col_src,
                                                   float* __restrict__ exarr,
                                                   float* __restrict__ invden) {
    int v = blockIdx.x * (blockDim.x >> 6) + (threadIdx.x >> 6);
    int lane = threadIdx.x & 63;
    if (v >= NN) return;
    int start = row_ptr[v], end = row_ptr[v + 1];
    int deg = end - start;
    float erd[H];
#pragma unroll
    for (int h = 0; h < H; ++h) erd[h] = er[(size_t)v * H + h];

    if (deg <= 64) {
        int i = start + lane;
        bool valid = lane < deg;
        int s = col_src[valid ? i : start];
        float e[H];
#pragma unroll
        for (int h = 0; h < H; ++h) {
            float x = el[(size_t)s * H + h] + erd[h];
            x = (x >= 0.f) ? x : NEG_SLOPE * x;
            e[h] = valid ? x : -1e30f;
        }
        float inv[H];
#pragma unroll
        for (int h = 0; h < H; ++h) {
            float m = wave_max(e[h]);
            float ex = valid ? __expf(e[h] - m) : 0.f;
            float den = wave_sum(ex);
            inv[h] = 1.f / den;
            e[h] = ex;  // reuse reg
        }
        if (valid) {
            if (H == 4) {
                *(float4*)&exarr[(size_t)i * 4] = make_float4(e[0], e[1], e[2], e[3]);
            } else {
                exarr[i] = e[0];
            }
        }
        if (lane == 0) {
#pragma unroll
            for (int h = 0; h < H; ++h) invden[(size_t)v * H + h] = inv[h];
        }
    } else {
        // general path (rare): two passes with regather
        float m[H];
#pragma unroll
        for (int h = 0; h < H; ++h) m[h] = -1e30f;
        for (int base = start; base < end; base += 64) {
            int i = base + lane;
            bool valid = i < end;
            int s = col_src[valid ? i : start];
#pragma unroll
            for (int h = 0; h < H; ++h) {
                float x = el[(size_t)s * H + h] + erd[h];
                x = (x >= 0.f) ? x : NEG_SLOPE * x;
                m[h] = fmaxf(m[h], valid ? x : -1e30f);
            }
        }
#pragma unroll
        for (int h = 0; h < H; ++h) m[h] = wave_max(m[h]);
        float den[H];
#pragma unroll
        for (int h = 0; h < H; ++h) den[h] = 0.f;
        for (int base = start; base < end; base += 64) {
            int i = base + lane;
            bool valid = i < end;
            int s = col_src[valid ? i : start];
            float ex[H];
#pragma unroll
            for (int h = 0; h < H; ++h) {
                float x = el[(size_t)s * H + h] + erd[h];
                x = (x >= 0.f) ? x : NEG_SLOPE * x;
                ex[h] = valid ? __expf(x - m[h]) : 0.f;
                den[h] += ex[h];
            }
            if (valid) {
                if (H == 4) {
                    *(float4*)&exarr[(size_t)i * 4] = make_float4(ex[0], ex[1], ex[2], ex[3]);
                } else {
                    exarr[i] = ex[0];
                }
            }
        }
        if (H == 4) {
#pragma unroll
            for (int h = 0; h < H; ++h) den[h] = wave_sum(den[h]);
            if (lane == 0) {
#pragma unroll
                for (int h = 0; h < H; ++h) invden[(size_t)v * H + h] = 1.f / den[h];
            }
        } else {
            float d = wave_sum(den[0]);
            if (lane == 0) invden[v] = 1.f / d;
        }
    }
}

// ---------------- aggregation: pure SpMM, one wave per dst, lane = feature ----------------
template <int H>
__global__ __launch_bounds__(256) void agg_kernel(const float* __restrict__ z,
                                                  const float* __restrict__ exarr,
                                                  const float* __restrict__ invden,
                                                  const int* __restrict__ row_ptr,
                                                  const int* __restrict__ col_src,
                                                  float* __restrict__ out) {
    int v = blockIdx.x * (blockDim.x >> 6) + (threadIdx.x >> 6);
    int lane = threadIdx.x & 63;
    if (v >= NN) return;
    int start = row_ptr[v], end = row_ptr[v + 1];
    float acc[H];
#pragma unroll
    for (int h = 0; h < H; ++h) acc[h] = 0.f;

    int i = start;
    for (; i + 4 <= end; i += 4) {
        int s0 = col_src[i + 0];
        int s1 = col_src[i + 1];
        int s2 = col_src[i + 2];
        int s3 = col_src[i + 3];
        float w0[H], w1[H], w2[H], w3[H];
        float z0[H], z1[H], z2[H], z3[H];
#pragma unroll
        for (int h = 0; h < H; ++h) {
            w0[h] = exarr[(size_t)(i + 0) * H + h];
            w1[h] = exarr[(size_t)(i + 1) * H + h];
            w2[h] = exarr[(size_t)(i + 2) * H + h];
            w3[h] = exarr[(size_t)(i + 3) * H + h];
            z0[h] = z[(size_t)s0 * H * DD + h * DD + lane];
            z1[h] = z[(size_t)s1 * H * DD + h * DD + lane];
            z2[h] = z[(size_t)s2 * H * DD + h * DD + lane];
            z3[h] = z[(size_t)s3 * H * DD + h * DD + lane];
        }
#pragma unroll
        for (int h = 0; h < H; ++h) {
            acc[h] += w0[h] * z0[h];
            acc[h] += w1[h] * z1[h];
            acc[h] += w2[h] * z2[h];
            acc[h] += w3[h] * z3[h];
        }
    }
    for (; i < end; ++i) {
        int s = col_src[i];
#pragma unroll
        for (int h = 0; h < H; ++h) {
            acc[h] += exarr[(size_t)i * H + h] * z[(size_t)s * H * DD + h * DD + lane];
        }
    }
#pragma unroll
    for (int h = 0; h < H; ++h) {
        float r = acc[h] * invden[(size_t)v * H + h];
        out[(size_t)v * H * DD + h * DD + lane] = (r > 0.f) ? r : 0.f;  // fused ReLU
    }
}

// ---------------- pooling ----------------
__device__ inline int lower_bound_dev(const int* a, int n, int v) {
    int lo = 0, hi = n;
    while (lo < hi) {
        int mid = (lo + hi) >> 1;
        if (a[mid] < v) lo = mid + 1; else hi = mid;
    }
    return lo;
}

__global__ __launch_bounds__(256) void pool_kernel(const float* __restrict__ x,
                                                   const int* __restrict__ gid,
                                                   float* __restrict__ pooled,
                                                   float* __restrict__ gcnt) {
    int g = blockIdx.x;
    int start = lower_bound_dev(gid, NN, g);
    int end = lower_bound_dev(gid, NN, g + 1);
    int lane = threadIdx.x & 63;
    int w = threadIdx.x >> 6;
    float acc = 0.f;
    for (int i = start + w; i < end; i += 4) acc += x[(size_t)i * DD + lane];
    __shared__ float red[4][DD];
    red[w][lane] = acc;
    __syncthreads();
    if (w == 0) {
        float s = red[0][lane] + red[1][lane] + red[2][lane] + red[3][lane];
        pooled[g * DD + lane] = s;
        if (lane == 0) gcnt[g] = (float)(end - start);
    }
}

// ---------------- head ----------------
__global__ __launch_bounds__(64) void head_kernel(const float* __restrict__ pooled,
                                                  const float* __restrict__ gcnt,
                                                  const float* __restrict__ fc1w,
                                                  const float* __restrict__ fc1b,
                                                  const float* __restrict__ fc2w,
                                                  const float* __restrict__ fc2b,
                                                  float* __restrict__ out) {
    __shared__ float P[GG][DD + 1];
    __shared__ float Y1[GG][DD + 1];
    int g = threadIdx.x;
    float c = fmaxf(gcnt[g], 1.0f);
    for (int k = 0; k < DD; ++k) P[g][k] = pooled[g * DD + k] / c;
    __syncthreads();
    for (int j = 0; j < DD; ++j) {
        float s = fc1b[j];
        for (int k = 0; k < DD; ++k) s += P[g][k] * fc1w[k * DD + j];
        Y1[g][j] = (s > 0.f) ? s : expm1f(s);
    }
    __syncthreads();
    float y2[CC];
    for (int c2 = 0; c2 < CC; ++c2) {
        float s = fc2b[c2];
        for (int j = 0; j < DD; ++j) s += Y1[g][j] * fc2w[j * CC + c2];
        y2[c2] = s;
    }
    for (int c2 = 0; c2 < CC; ++c2) {
        float m = y2[c2];
#pragma unroll
        for (int o = 32; o > 0; o >>= 1) m = fmaxf(m, __shfl_xor(m, o));
        float sexp = __expf(y2[c2] - m);
#pragma unroll
        for (int o = 32; o > 0; o >>= 1) sexp += __shfl_xor(sexp, o);
        out[g * CC + c2] = y2[c2] - m - logf(sexp);
    }
}

// ---------------- launcher ----------------
extern "C" void kernel_launch(void* const* d_in, const int* in_sizes, int n_in,
                              void* d_out, int out_size, void* d_ws, size_t ws_size,
                              hipStream_t stream) {
    const float* h    = (const float*)d_in[0];
    const int* src    = (const int*)d_in[1];
    const int* dst    = (const int*)d_in[2];
    const int* gid    = (const int*)d_in[3];
    const float* W0   = (const float*)d_in[4];
    const float* al0  = (const float*)d_in[5];
    const float* ar0  = (const float*)d_in[6];
    const float* W1   = (const float*)d_in[7];
    const float* al1  = (const float*)d_in[8];
    const float* ar1  = (const float*)d_in[9];
    const float* W2   = (const float*)d_in[10];
    const float* al2  = (const float*)d_in[11];
    const float* ar2  = (const float*)d_in[12];
    const float* W3   = (const float*)d_in[13];
    const float* al3  = (const float*)d_in[14];
    const float* ar3  = (const float*)d_in[15];
    const float* fc1w = (const float*)d_in[16];
    const float* fc1b = (const float*)d_in[17];
    const float* fc2w = (const float*)d_in[18];
    const float* fc2b = (const float*)d_in[19];
    const int E = in_sizes[1];

    char* wsb = (char*)d_ws;
    size_t off = 0;
    auto alloc = [&](size_t bytes) -> void* {
        void* p = wsb + off;
        off = (off + bytes + 255) & ~(size_t)255;
        return p;
    };
    float* bufA    = (float*)alloc((size_t)NN * 256 * 4);
    float* bufZ    = (float*)alloc((size_t)NN * 256 * 4);
    float* el      = (float*)alloc((size_t)NN * HH * 4);
    float* er      = (float*)alloc((size_t)NN * HH * 4);
    int*   counts  = (int*)alloc((size_t)NN * 4);
    int*   row_ptr = (int*)alloc((size_t)(NN + 1) * 4);
    int*   fill    = (int*)alloc((size_t)NN * 4);
    int*   col_src = (int*)alloc((size_t)E * 4);
    float* exarr   = (float*)alloc((size_t)E * HH * 4);
    float* invden  = (float*)alloc((size_t)NN * HH * 4);
    float* pooled  = (float*)alloc((size_t)GG * DD * 4);
    float* gcnt    = (float*)alloc((size_t)GG * 4);

    // ---- CSR build ----
    hipMemsetAsync(counts, 0, (size_t)NN * 4, stream);
    int eg = (E + 255) / 256;
    hist_kernel<<<eg, 256, 0, stream>>>(dst, E, counts);
    scan_kernel<<<1, 1024, 0, stream>>>(counts, row_ptr, fill, NN, E);
    scatter_kernel<<<eg, 256, 0, stream>>>(src, dst, E, fill, col_src);

    const int gemmGridM = (NN + 63) / 64;
    const int waveBlocks = (NN + 3) / 4;

    // ---- layer 0 ----
    gemm_f32_eler<<<dim3(gemmGridM, 4), 256, 0, stream>>>(h, W0, bufZ, al0, ar0, el, er, NN, 256, IN_F, 4);
    attn_kernel<4><<<waveBlocks, 256, 0, stream>>>(el, er, row_ptr, col_src, exarr, invden);
    agg_kernel<4><<<waveBlocks, 256, 0, stream>>>(bufZ, exarr, invden, row_ptr, col_src, bufA);

    // ---- layer 1 ----
    gemm_f32_eler<<<dim3(gemmGridM, 4), 256, 0, stream>>>(bufA, W1, bufZ, al1, ar1, el, er, NN, 256, 256, 4);
    attn_kernel<4><<<waveBlocks, 256, 0, stream>>>(el, er, row_ptr, col_src, exarr, invden);
    agg_kernel<4><<<waveBlocks, 256, 0, stream>>>(bufZ, exarr, invden, row_ptr, col_src, bufA);

    // ---- layer 2 ----
    gemm_f32_eler<<<dim3(gemmGridM, 4), 256, 0, stream>>>(bufA, W2, bufZ, al2, ar2, el, er, NN, 256, 256, 4);
    attn_kernel<4><<<waveBlocks, 256, 0, stream>>>(el, er, row_ptr, col_src, exarr, invden);
    agg_kernel<4><<<waveBlocks, 256, 0, stream>>>(bufZ, exarr, invden, row_ptr, col_src, bufA);

    // ---- layer 3 (H=1) ----
    gemm_f32_eler<<<dim3(gemmGridM, 1), 256, 0, stream>>>(bufA, W3, bufZ, al3, ar3, el, er, NN, 64, 256, 1);
    attn_kernel<1><<<waveBlocks, 256, 0, stream>>>(el, er, row_ptr, col_src, exarr, invden);
    agg_kernel<1><<<waveBlocks, 256, 0, stream>>>(bufZ, exarr, invden, row_ptr, col_src, bufA);

    // ---- pooling + head ----
    pool_kernel<<<GG, 256, 0, stream>>>(bufA, gid, pooled, gcnt);
    head_kernel<<<1, 64, 0, stream>>>(pooled, gcnt, fc1w, fc1b, fc2w, fc2b, (float*)d_out);
}

// Round 4
// 1055.888 us; speedup vs baseline: 1.3876x; 1.0905x over previous
//
#include <hip/hip_runtime.h>
#include <hip/hip_bf16.h>
#include <math.h>

#define NN 50000
#define IN_F 128
#define DD 64
#define HH 4
#define CC 10
#define GG 64
#define NEG_SLOPE 0.2f

typedef __attribute__((ext_vector_type(8))) short bf16x8;
typedef __attribute__((ext_vector_type(4))) float f32x4;

__device__ inline ushort f2bf(float f) {
    unsigned u = __float_as_uint(f);
    unsigned r = (u + 0x7fffu + ((u >> 16) & 1u)) >> 16;
    return (ushort)r;
}
__device__ inline float bf2f(ushort b) { return __uint_as_float(((unsigned)b) << 16); }

// ---------------- wave helpers ----------------
__device__ inline float wave_max(float v) {
#pragma unroll
    for (int o = 32; o > 0; o >>= 1) v = fmaxf(v, __shfl_xor(v, o));
    return v;
}
__device__ inline float wave_sum(float v) {
#pragma unroll
    for (int o = 32; o > 0; o >>= 1) v += __shfl_xor(v, o);
    return v;
}

// ---------------- CSR build ----------------
__global__ void hist_kernel(const int* __restrict__ dst, int E, int* __restrict__ counts) {
    int i = blockIdx.x * blockDim.x + threadIdx.x;
    if (i < E) atomicAdd(&counts[dst[i]], 1);
}

__global__ __launch_bounds__(1024) void scan_kernel(const int* __restrict__ counts,
                                                    int* __restrict__ row_ptr,
                                                    int* __restrict__ fill,
                                                    int n, int E) {
    __shared__ int sums[1024];
    int t = threadIdx.x;
    int chunk = (n + 1023) / 1024;
    int lo = t * chunk;
    int hi = min(lo + chunk, n);
    int s = 0;
    for (int i = lo; i < hi; ++i) s += counts[i];
    sums[t] = s;
    __syncthreads();
    for (int o = 1; o < 1024; o <<= 1) {
        int u = (t >= o) ? sums[t - o] : 0;
        __syncthreads();
        sums[t] += u;
        __syncthreads();
    }
    int base = sums[t] - s;  // exclusive prefix
    for (int i = lo; i < hi; ++i) {
        int c = counts[i];
        row_ptr[i] = base;
        fill[i] = base;
        base += c;
    }
    if (t == 0) row_ptr[n] = E;
}

__global__ void scatter_kernel(const int* __restrict__ src, const int* __restrict__ dst,
                               int E, int* __restrict__ fill, int* __restrict__ col_src) {
    int i = blockIdx.x * blockDim.x + threadIdx.x;
    if (i < E) {
        int p = atomicAdd(&fill[dst[i]], 1);
        col_src[p] = src[i];
    }
}

// ---------------- fp32 -> bf16 hi/lo split (for layer-0 input h) ----------------
__global__ void hconv_kernel(const float* __restrict__ in, ushort* __restrict__ hi,
                             ushort* __restrict__ lo, int n) {
    int i = blockIdx.x * blockDim.x + threadIdx.x;
    if (i < n) {
        float v = in[i];
        ushort hb = f2bf(v);
        hi[i] = hb;
        lo[i] = f2bf(v - bf2f(hb));
    }
}

// ---------------- W -> transposed, k-blocked, bf16 hi/lo: Wt[kb][n][kk] ----------------
__global__ void wconv_kernel(const float* __restrict__ W, int K, int N,
                             ushort* __restrict__ thi, ushort* __restrict__ tlo) {
    int i = blockIdx.x * blockDim.x + threadIdx.x;
    if (i >= K * N) return;
    int k = i / N, n = i - k * N;
    float v = W[i];
    ushort hb = f2bf(v);
    size_t o = ((size_t)(k >> 5) * N + n) * 32 + (k & 31);
    thi[o] = hb;
    tlo[o] = f2bf(v - bf2f(hb));
}

// ---------------- MFMA GEMM (bf16 split, 64xN blocks) + fused el/er ----------------
// A: hi/lo bf16 [M][K]; W: blocked [K/32][N][32] hi/lo; C fp32 [M][N].
// block = 256 threads = 4 waves; wave w owns rows bm+16w..+15, all N cols.
template <int N, int H>
__global__ __launch_bounds__(256) void gemm_mfma_eler(
    const ushort* __restrict__ Ahi, const ushort* __restrict__ Alo,
    const ushort* __restrict__ Wthi, const ushort* __restrict__ Wtlo,
    float* __restrict__ C, const float* __restrict__ al, const float* __restrict__ ar,
    float* __restrict__ el, float* __restrict__ er, int M, int K) {
    constexpr int NT = N / 16;
    __shared__ ushort Bh[N][40];  // padded row (80B) -> uniform bank spread
    __shared__ ushort Bl[N][40];
    const int t = threadIdx.x;
    const int w = t >> 6, lane = t & 63;
    const int cl = lane & 15, g = lane >> 4;
    const int bm = blockIdx.x * 64;
    const int arow = bm + 16 * w + cl;
    const bool aval = arow < M;
    const size_t abase = (size_t)arow * K;

    f32x4 acc[NT];
#pragma unroll
    for (int nt = 0; nt < NT; ++nt) acc[nt] = (f32x4){0.f, 0.f, 0.f, 0.f};

    const int nkb = K >> 5;
    for (int kb = 0; kb < nkb; ++kb) {
        __syncthreads();
        if (t < N) {
            const float4* gsh = (const float4*)(Wthi + ((size_t)kb * N + t) * 32);
            const float4* gsl = (const float4*)(Wtlo + ((size_t)kb * N + t) * 32);
            float4* dh = (float4*)&Bh[t][0];
            float4* dl = (float4*)&Bl[t][0];
#pragma unroll
            for (int q = 0; q < 4; ++q) { dh[q] = gsh[q]; dl[q] = gsl[q]; }
        }
        __syncthreads();
        bf16x8 a_hi = {0, 0, 0, 0, 0, 0, 0, 0};
        bf16x8 a_lo = {0, 0, 0, 0, 0, 0, 0, 0};
        if (aval) {
            a_hi = *(const bf16x8*)(Ahi + abase + kb * 32 + g * 8);
            a_lo = *(const bf16x8*)(Alo + abase + kb * 32 + g * 8);
        }
#pragma unroll
        for (int nt = 0; nt < NT; ++nt) {
            bf16x8 b_hi = *(const bf16x8*)&Bh[16 * nt + cl][g * 8];
            bf16x8 b_lo = *(const bf16x8*)&Bl[16 * nt + cl][g * 8];
            acc[nt] = __builtin_amdgcn_mfma_f32_16x16x32_bf16(a_hi, b_hi, acc[nt], 0, 0, 0);
            acc[nt] = __builtin_amdgcn_mfma_f32_16x16x32_bf16(a_lo, b_hi, acc[nt], 0, 0, 0);
            acc[nt] = __builtin_amdgcn_mfma_f32_16x16x32_bf16(a_hi, b_lo, acc[nt], 0, 0, 0);
        }
    }

    // C store: lane holds C[r0+j][16nt+cl], r0 = bm+16w+4g
    const int r0 = bm + 16 * w + 4 * g;
#pragma unroll
    for (int nt = 0; nt < NT; ++nt) {
#pragma unroll
        for (int j = 0; j < 4; ++j) {
            int r = r0 + j;
            if (r < M) C[(size_t)r * N + 16 * nt + cl] = acc[nt][j];
        }
    }
    // fused el/er: head h = cols 64h..64h+63 = tiles 4h..4h+3
#pragma unroll
    for (int h = 0; h < H; ++h) {
        float pl[4] = {0.f, 0.f, 0.f, 0.f};
        float pr[4] = {0.f, 0.f, 0.f, 0.f};
#pragma unroll
        for (int tt = 0; tt < 4; ++tt) {
            int nt = 4 * h + tt;
            float av = al[h * DD + 16 * tt + cl];
            float rv = ar[h * DD + 16 * tt + cl];
#pragma unroll
            for (int j = 0; j < 4; ++j) {
                pl[j] += acc[nt][j] * av;
                pr[j] += acc[nt][j] * rv;
            }
        }
#pragma unroll
        for (int j = 0; j < 4; ++j) {
#pragma unroll
            for (int o = 1; o < 16; o <<= 1) {
                pl[j] += __shfl_xor(pl[j], o);
                pr[j] += __shfl_xor(pr[j], o);
            }
        }
        if (cl == 0) {
#pragma unroll
            for (int j = 0; j < 4; ++j) {
                int r = r0 + j;
                if (r < M) {
                    el[(size_t)r * H + h] = pl[j];
                    er[(size_t)r * H + h] = pr[j];
                }
            }
        }
    }
}

// ---------------- attention weights: one wave per dst, lane = edge ----------------
template <int H>
__global__ __launch_bounds__(256) void attn_kernel(const float* __restrict__ el,
                                                   const float* __restrict__ er,
                                                   const int* __restrict__ row_ptr,
                                                   const int* __restrict__ col_src,
                                                   float* __restrict__ exarr,
                                                   float* __restrict__ invden) {
    int v = blockIdx.x * (blockDim.x >> 6) + (threadIdx.x >> 6);
    int lane = threadIdx.x & 63;
    if (v >= NN) return;
    int start = row_ptr[v], end = row_ptr[v + 1];
    int deg = end - start;
    float erd[H];
#pragma unroll
    for (int h = 0; h < H; ++h) erd[h] = er[(size_t)v * H + h];

    if (deg <= 64) {
        int i = start + lane;
        bool valid = lane < deg;
        int s = col_src[valid ? i : start];
        float e[H];
#pragma unroll
        for (int h = 0; h < H; ++h) {
            float x = el[(size_t)s * H + h] + erd[h];
            x = (x >= 0.f) ? x : NEG_SLOPE * x;
            e[h] = valid ? x : -1e30f;
        }
        float inv[H];
#pragma unroll
        for (int h = 0; h < H; ++h) {
            float m = wave_max(e[h]);
            float ex = valid ? __expf(e[h] - m) : 0.f;
            float den = wave_sum(ex);
            inv[h] = 1.f / den;
            e[h] = ex;
        }
        if (valid) {
            if (H == 4) {
                *(float4*)&exarr[(size_t)i * 4] = make_float4(e[0], e[1], e[2], e[3]);
            } else {
                exarr[i] = e[0];
            }
        }
        if (lane == 0) {
#pragma unroll
            for (int h = 0; h < H; ++h) invden[(size_t)v * H + h] = inv[h];
        }
    } else {
        float m[H];
#pragma unroll
        for (int h = 0; h < H; ++h) m[h] = -1e30f;
        for (int base = start; base < end; base += 64) {
            int i = base + lane;
            bool valid = i < end;
            int s = col_src[valid ? i : start];
#pragma unroll
            for (int h = 0; h < H; ++h) {
                float x = el[(size_t)s * H + h] + erd[h];
                x = (x >= 0.f) ? x : NEG_SLOPE * x;
                m[h] = fmaxf(m[h], valid ? x : -1e30f);
            }
        }
#pragma unroll
        for (int h = 0; h < H; ++h) m[h] = wave_max(m[h]);
        float den[H];
#pragma unroll
        for (int h = 0; h < H; ++h) den[h] = 0.f;
        for (int base = start; base < end; base += 64) {
            int i = base + lane;
            bool valid = i < end;
            int s = col_src[valid ? i : start];
            float ex[H];
#pragma unroll
            for (int h = 0; h < H; ++h) {
                float x = el[(size_t)s * H + h] + erd[h];
                x = (x >= 0.f) ? x : NEG_SLOPE * x;
                ex[h] = valid ? __expf(x - m[h]) : 0.f;
                den[h] += ex[h];
            }
            if (valid) {
                if (H == 4) {
                    *(float4*)&exarr[(size_t)i * 4] = make_float4(ex[0], ex[1], ex[2], ex[3]);
                } else {
                    exarr[i] = ex[0];
                }
            }
        }
#pragma unroll
        for (int h = 0; h < H; ++h) den[h] = wave_sum(den[h]);
        if (lane == 0) {
#pragma unroll
            for (int h = 0; h < H; ++h) invden[(size_t)v * H + h] = 1.f / den[h];
        }
    }
}

// ---------------- aggregation: pure SpMM; optionally writes bf16 hi/lo split ----------------
template <int H, bool SPLIT>
__global__ __launch_bounds__(256) void agg_kernel(const float* __restrict__ z,
                                                  const float* __restrict__ exarr,
                                                  const float* __restrict__ invden,
                                                  const int* __restrict__ row_ptr,
                                                  const int* __restrict__ col_src,
                                                  float* __restrict__ outf,
                                                  ushort* __restrict__ ohi,
                                                  ushort* __restrict__ olo) {
    int v = blockIdx.x * (blockDim.x >> 6) + (threadIdx.x >> 6);
    int lane = threadIdx.x & 63;
    if (v >= NN) return;
    int start = row_ptr[v], end = row_ptr[v + 1];
    float acc[H];
#pragma unroll
    for (int h = 0; h < H; ++h) acc[h] = 0.f;

    int i = start;
    for (; i + 4 <= end; i += 4) {
        int s0 = col_src[i + 0];
        int s1 = col_src[i + 1];
        int s2 = col_src[i + 2];
        int s3 = col_src[i + 3];
        float w0[H], w1[H], w2[H], w3[H];
        float z0[H], z1[H], z2[H], z3[H];
#pragma unroll
        for (int h = 0; h < H; ++h) {
            w0[h] = exarr[(size_t)(i + 0) * H + h];
            w1[h] = exarr[(size_t)(i + 1) * H + h];
            w2[h] = exarr[(size_t)(i + 2) * H + h];
            w3[h] = exarr[(size_t)(i + 3) * H + h];
            z0[h] = z[(size_t)s0 * H * DD + h * DD + lane];
            z1[h] = z[(size_t)s1 * H * DD + h * DD + lane];
            z2[h] = z[(size_t)s2 * H * DD + h * DD + lane];
            z3[h] = z[(size_t)s3 * H * DD + h * DD + lane];
        }
#pragma unroll
        for (int h = 0; h < H; ++h) {
            acc[h] += w0[h] * z0[h];
            acc[h] += w1[h] * z1[h];
            acc[h] += w2[h] * z2[h];
            acc[h] += w3[h] * z3[h];
        }
    }
    for (; i < end; ++i) {
        int s = col_src[i];
#pragma unroll
        for (int h = 0; h < H; ++h) {
            acc[h] += exarr[(size_t)i * H + h] * z[(size_t)s * H * DD + h * DD + lane];
        }
    }
#pragma unroll
    for (int h = 0; h < H; ++h) {
        float r = acc[h] * invden[(size_t)v * H + h];
        r = (r > 0.f) ? r : 0.f;  // fused ReLU
        size_t idx = (size_t)v * H * DD + h * DD + lane;
        if (SPLIT) {
            ushort hb = f2bf(r);
            ohi[idx] = hb;
            olo[idx] = f2bf(r - bf2f(hb));
        } else {
            outf[idx] = r;
        }
    }
}

// ---------------- pooling ----------------
__device__ inline int lower_bound_dev(const int* a, int n, int v) {
    int lo = 0, hi = n;
    while (lo < hi) {
        int mid = (lo + hi) >> 1;
        if (a[mid] < v) lo = mid + 1; else hi = mid;
    }
    return lo;
}

__global__ __launch_bounds__(256) void pool_kernel(const float* __restrict__ x,
                                                   const int* __restrict__ gid,
                                                   float* __restrict__ pooled,
                                                   float* __restrict__ gcnt) {
    int g = blockIdx.x;
    int start = lower_bound_dev(gid, NN, g);
    int end = lower_bound_dev(gid, NN, g + 1);
    int lane = threadIdx.x & 63;
    int w = threadIdx.x >> 6;
    float acc = 0.f;
    for (int i = start + w; i < end; i += 4) acc += x[(size_t)i * DD + lane];
    __shared__ float red[4][DD];
    red[w][lane] = acc;
    __syncthreads();
    if (w == 0) {
        float s = red[0][lane] + red[1][lane] + red[2][lane] + red[3][lane];
        pooled[g * DD + lane] = s;
        if (lane == 0) gcnt[g] = (float)(end - start);
    }
}

// ---------------- head ----------------
__global__ __launch_bounds__(64) void head_kernel(const float* __restrict__ pooled,
                                                  const float* __restrict__ gcnt,
                                                  const float* __restrict__ fc1w,
                                                  const float* __restrict__ fc1b,
                                                  const float* __restrict__ fc2w,
                                                  const float* __restrict__ fc2b,
                                                  float* __restrict__ out) {
    __shared__ float P[GG][DD + 1];
    __shared__ float Y1[GG][DD + 1];
    int g = threadIdx.x;
    float c = fmaxf(gcnt[g], 1.0f);
    for (int k = 0; k < DD; ++k) P[g][k] = pooled[g * DD + k] / c;
    __syncthreads();
    for (int j = 0; j < DD; ++j) {
        float s = fc1b[j];
        for (int k = 0; k < DD; ++k) s += P[g][k] * fc1w[k * DD + j];
        Y1[g][j] = (s > 0.f) ? s : expm1f(s);
    }
    __syncthreads();
    float y2[CC];
    for (int c2 = 0; c2 < CC; ++c2) {
        float s = fc2b[c2];
        for (int j = 0; j < DD; ++j) s += Y1[g][j] * fc2w[j * CC + c2];
        y2[c2] = s;
    }
    for (int c2 = 0; c2 < CC; ++c2) {
        float m = y2[c2];
#pragma unroll
        for (int o = 32; o > 0; o >>= 1) m = fmaxf(m, __shfl_xor(m, o));
        float sexp = __expf(y2[c2] - m);
#pragma unroll
        for (int o = 32; o > 0; o >>= 1) sexp += __shfl_xor(sexp, o);
        out[g * CC + c2] = y2[c2] - m - logf(sexp);
    }
}

// ---------------- launcher ----------------
extern "C" void kernel_launch(void* const* d_in, const int* in_sizes, int n_in,
                              void* d_out, int out_size, void* d_ws, size_t ws_size,
                              hipStream_t stream) {
    const float* h    = (const float*)d_in[0];
    const int* src    = (const int*)d_in[1];
    const int* dst    = (const int*)d_in[2];
    const int* gid    = (const int*)d_in[3];
    const float* W0   = (const float*)d_in[4];
    const float* al0  = (const float*)d_in[5];
    const float* ar0  = (const float*)d_in[6];
    const float* W1   = (const float*)d_in[7];
    const float* al1  = (const float*)d_in[8];
    const float* ar1  = (const float*)d_in[9];
    const float* W2   = (const float*)d_in[10];
    const float* al2  = (const float*)d_in[11];
    const float* ar2  = (const float*)d_in[12];
    const float* W3   = (const float*)d_in[13];
    const float* al3  = (const float*)d_in[14];
    const float* ar3  = (const float*)d_in[15];
    const float* fc1w = (const float*)d_in[16];
    const float* fc1b = (const float*)d_in[17];
    const float* fc2w = (const float*)d_in[18];
    const float* fc2b = (const float*)d_in[19];
    const int E = in_sizes[1];

    char* wsb = (char*)d_ws;
    size_t off = 0;
    auto alloc = [&](size_t bytes) -> void* {
        void* p = wsb + off;
        off = (off + bytes + 255) & ~(size_t)255;
        return p;
    };
    float*  bufZ    = (float*)alloc((size_t)NN * 256 * 4);   // z (fp32)
    ushort* Ahi     = (ushort*)alloc((size_t)NN * 256 * 2);  // GEMM A input hi
    ushort* Alo     = (ushort*)alloc((size_t)NN * 256 * 2);  // GEMM A input lo
    float*  bufA    = (float*)alloc((size_t)NN * DD * 4);    // layer-3 output (fp32, for pool)
    float*  el      = (float*)alloc((size_t)NN * HH * 4);
    float*  er      = (float*)alloc((size_t)NN * HH * 4);
    int*    counts  = (int*)alloc((size_t)NN * 4);
    int*    row_ptr = (int*)alloc((size_t)(NN + 1) * 4);
    int*    fill    = (int*)alloc((size_t)NN * 4);
    int*    col_src = (int*)alloc((size_t)E * 4);
    float*  exarr   = (float*)alloc((size_t)E * HH * 4);
    float*  invden  = (float*)alloc((size_t)NN * HH * 4);
    float*  pooled  = (float*)alloc((size_t)GG * DD * 4);
    float*  gcnt    = (float*)alloc((size_t)GG * 4);
    ushort* w0h     = (ushort*)alloc((size_t)IN_F * 256 * 2);
    ushort* w0l     = (ushort*)alloc((size_t)IN_F * 256 * 2);
    ushort* w1h     = (ushort*)alloc((size_t)256 * 256 * 2);
    ushort* w1l     = (ushort*)alloc((size_t)256 * 256 * 2);
    ushort* w2h     = (ushort*)alloc((size_t)256 * 256 * 2);
    ushort* w2l     = (ushort*)alloc((size_t)256 * 256 * 2);
    ushort* w3h     = (ushort*)alloc((size_t)256 * 64 * 2);
    ushort* w3l     = (ushort*)alloc((size_t)256 * 64 * 2);

    // ---- CSR build ----
    hipMemsetAsync(counts, 0, (size_t)NN * 4, stream);
    int eg = (E + 255) / 256;
    hist_kernel<<<eg, 256, 0, stream>>>(dst, E, counts);
    scan_kernel<<<1, 1024, 0, stream>>>(counts, row_ptr, fill, NN, E);
    scatter_kernel<<<eg, 256, 0, stream>>>(src, dst, E, fill, col_src);

    // ---- weight + input conversions ----
    wconv_kernel<<<(IN_F * 256 + 255) / 256, 256, 0, stream>>>(W0, IN_F, 256, w0h, w0l);
    wconv_kernel<<<(256 * 256 + 255) / 256, 256, 0, stream>>>(W1, 256, 256, w1h, w1l);
    wconv_kernel<<<(256 * 256 + 255) / 256, 256, 0, stream>>>(W2, 256, 256, w2h, w2l);
    wconv_kernel<<<(256 * 64 + 255) / 256, 256, 0, stream>>>(W3, 256, 64, w3h, w3l);
    hconv_kernel<<<(NN * IN_F + 255) / 256, 256, 0, stream>>>(h, Ahi, Alo, NN * IN_F);

    const int gemmGrid = (NN + 63) / 64;  // 782
    const int waveBlocks = (NN + 3) / 4;  // 12500

    // ---- layer 0 (K=128, N=256, H=4) ----
    gemm_mfma_eler<256, 4><<<gemmGrid, 256, 0, stream>>>(Ahi, Alo, w0h, w0l, bufZ, al0, ar0, el, er, NN, IN_F);
    attn_kernel<4><<<waveBlocks, 256, 0, stream>>>(el, er, row_ptr, col_src, exarr, invden);
    agg_kernel<4, true><<<waveBlocks, 256, 0, stream>>>(bufZ, exarr, invden, row_ptr, col_src, nullptr, Ahi, Alo);

    // ---- layer 1 ----
    gemm_mfma_eler<256, 4><<<gemmGrid, 256, 0, stream>>>(Ahi, Alo, w1h, w1l, bufZ, al1, ar1, el, er, NN, 256);
    attn_kernel<4><<<waveBlocks, 256, 0, stream>>>(el, er, row_ptr, col_src, exarr, invden);
    agg_kernel<4, true><<<waveBlocks, 256, 0, stream>>>(bufZ, exarr, invden, row_ptr, col_src, nullptr, Ahi, Alo);

    // ---- layer 2 ----
    gemm_mfma_eler<256, 4><<<gemmGrid, 256, 0, stream>>>(Ahi, Alo, w2h, w2l, bufZ, al2, ar2, el, er, NN, 256);
    attn_kernel<4><<<waveBlocks, 256, 0, stream>>>(el, er, row_ptr, col_src, exarr, invden);
    agg_kernel<4, true><<<waveBlocks, 256, 0, stream>>>(bufZ, exarr, invden, row_ptr, col_src, nullptr, Ahi, Alo);

    // ---- layer 3 (K=256, N=64, H=1) ----
    gemm_mfma_eler<64, 1><<<gemmGrid, 256, 0, stream>>>(Ahi, Alo, w3h, w3l, bufZ, al3, ar3, el, er, NN, 256);
    attn_kernel<1><<<waveBlocks, 256, 0, stream>>>(el, er, row_ptr, col_src, exarr, invden);
    agg_kernel<1, false><<<waveBlocks, 256, 0, stream>>>(bufZ, exarr, invden, row_ptr, col_src, bufA, nullptr, nullptr);

    // ---- pooling + head ----
    pool_kernel<<<GG, 256, 0, stream>>>(bufA, gid, pooled, gcnt);
    head_kernel<<<1, 64, 0, stream>>>(pooled, gcnt, fc1w, fc1b, fc2w, fc2b, (float*)d_out);
}

// Round 5
// 910.703 us; speedup vs baseline: 1.6089x; 1.1594x over previous
//
#include <hip/hip_runtime.h>
#include <hip/hip_bf16.h>
#include <math.h>

#define NN 50000
#define IN_F 128
#define DD 64
#define HH 4
#define CC 10
#define GG 64
#define NEG_SLOPE 0.2f

typedef __attribute__((ext_vector_type(8))) short bf16x8;
typedef __attribute__((ext_vector_type(4))) float f32x4;
typedef __attribute__((ext_vector_type(4))) unsigned short u16x4;

__device__ inline ushort f2bf(float f) {
    unsigned u = __float_as_uint(f);
    unsigned r = (u + 0x7fffu + ((u >> 16) & 1u)) >> 16;
    return (ushort)r;
}
__device__ inline float bf2f(ushort b) { return __uint_as_float(((unsigned)b) << 16); }

// ---------------- wave helpers ----------------
__device__ inline float wave_max(float v) {
#pragma unroll
    for (int o = 32; o > 0; o >>= 1) v = fmaxf(v, __shfl_xor(v, o));
    return v;
}
__device__ inline float wave_sum(float v) {
#pragma unroll
    for (int o = 32; o > 0; o >>= 1) v += __shfl_xor(v, o);
    return v;
}

// ---------------- CSR build ----------------
__global__ void hist_kernel(const int* __restrict__ dst, int E, int* __restrict__ counts) {
    int i = blockIdx.x * blockDim.x + threadIdx.x;
    if (i < E) atomicAdd(&counts[dst[i]], 1);
}

__global__ __launch_bounds__(1024) void scan_kernel(const int* __restrict__ counts,
                                                    int* __restrict__ row_ptr,
                                                    int* __restrict__ fill,
                                                    int n, int E) {
    __shared__ int sums[1024];
    int t = threadIdx.x;
    int chunk = (n + 1023) / 1024;
    int lo = t * chunk;
    int hi = min(lo + chunk, n);
    int s = 0;
    for (int i = lo; i < hi; ++i) s += counts[i];
    sums[t] = s;
    __syncthreads();
    for (int o = 1; o < 1024; o <<= 1) {
        int u = (t >= o) ? sums[t - o] : 0;
        __syncthreads();
        sums[t] += u;
        __syncthreads();
    }
    int base = sums[t] - s;  // exclusive prefix
    for (int i = lo; i < hi; ++i) {
        int c = counts[i];
        row_ptr[i] = base;
        fill[i] = base;
        base += c;
    }
    if (t == 0) row_ptr[n] = E;
}

__global__ void scatter_kernel(const int* __restrict__ src, const int* __restrict__ dst,
                               int E, int* __restrict__ fill, int* __restrict__ col_src) {
    int i = blockIdx.x * blockDim.x + threadIdx.x;
    if (i < E) {
        int p = atomicAdd(&fill[dst[i]], 1);
        col_src[p] = src[i];
    }
}

// ---------------- fp32 -> bf16 hi/lo split (for layer-0 input h) ----------------
__global__ void hconv_kernel(const float* __restrict__ in, ushort* __restrict__ hi,
                             ushort* __restrict__ lo, int n) {
    int i = blockIdx.x * blockDim.x + threadIdx.x;
    if (i < n) {
        float v = in[i];
        ushort hb = f2bf(v);
        hi[i] = hb;
        lo[i] = f2bf(v - bf2f(hb));
    }
}

// ---------------- W -> transposed, k-blocked, bf16 hi/lo: Wt[kb][n][kk] ----------------
__global__ void wconv_kernel(const float* __restrict__ W, int K, int N,
                             ushort* __restrict__ thi, ushort* __restrict__ tlo) {
    int i = blockIdx.x * blockDim.x + threadIdx.x;
    if (i >= K * N) return;
    int k = i / N, n = i - k * N;
    float v = W[i];
    ushort hb = f2bf(v);
    size_t o = ((size_t)(k >> 5) * N + n) * 32 + (k & 31);
    thi[o] = hb;
    tlo[o] = f2bf(v - bf2f(hb));
}

// ---------------- MFMA GEMM (bf16 split, 64xN blocks) + fused el/er ----------------
// A: hi/lo bf16 [M][K]; W: blocked [K/32][N][32] hi/lo.
// Output z as bf16: H=4 -> packed [r][d][h] (d=0..63, h=0..3); H=1 -> [r][d].
// block = 256 threads = 4 waves; wave w owns rows bm+16w..+15, all N cols.
template <int N, int H>
__global__ __launch_bounds__(256) void gemm_mfma_eler(
    const ushort* __restrict__ Ahi, const ushort* __restrict__ Alo,
    const ushort* __restrict__ Wthi, const ushort* __restrict__ Wtlo,
    ushort* __restrict__ zt, const float* __restrict__ al, const float* __restrict__ ar,
    float* __restrict__ el, float* __restrict__ er, int M, int K) {
    constexpr int NT = N / 16;
    __shared__ ushort Bh[N][34];  // 68B row stride (17 banks, odd) -> near-uniform spread
    __shared__ ushort Bl[N][34];
    const int t = threadIdx.x;
    const int w = t >> 6, lane = t & 63;
    const int cl = lane & 15, g = lane >> 4;
    const int bm = blockIdx.x * 64;
    const int arow = bm + 16 * w + cl;
    const bool aval = arow < M;
    const size_t abase = (size_t)arow * K;

    f32x4 acc[NT];
#pragma unroll
    for (int nt = 0; nt < NT; ++nt) acc[nt] = (f32x4){0.f, 0.f, 0.f, 0.f};

    const int nkb = K >> 5;
    for (int kb = 0; kb < nkb; ++kb) {
        __syncthreads();
        if (t < N) {
            const float4* gsh = (const float4*)(Wthi + ((size_t)kb * N + t) * 32);
            const float4* gsl = (const float4*)(Wtlo + ((size_t)kb * N + t) * 32);
#pragma unroll
            for (int q = 0; q < 4; ++q) {
                *(float4*)&Bh[t][q * 8] = gsh[q];
                *(float4*)&Bl[t][q * 8] = gsl[q];
            }
        }
        __syncthreads();
        bf16x8 a_hi = {0, 0, 0, 0, 0, 0, 0, 0};
        bf16x8 a_lo = {0, 0, 0, 0, 0, 0, 0, 0};
        if (aval) {
            a_hi = *(const bf16x8*)(Ahi + abase + kb * 32 + g * 8);
            a_lo = *(const bf16x8*)(Alo + abase + kb * 32 + g * 8);
        }
#pragma unroll
        for (int nt = 0; nt < NT; ++nt) {
            bf16x8 b_hi = *(const bf16x8*)&Bh[16 * nt + cl][g * 8];
            bf16x8 b_lo = *(const bf16x8*)&Bl[16 * nt + cl][g * 8];
            acc[nt] = __builtin_amdgcn_mfma_f32_16x16x32_bf16(a_hi, b_hi, acc[nt], 0, 0, 0);
            acc[nt] = __builtin_amdgcn_mfma_f32_16x16x32_bf16(a_lo, b_hi, acc[nt], 0, 0, 0);
            acc[nt] = __builtin_amdgcn_mfma_f32_16x16x32_bf16(a_hi, b_lo, acc[nt], 0, 0, 0);
        }
    }

    // z store (bf16). Lane holds C[r0+j][16nt+cl], r0 = bm+16w+4g.
    const int r0 = bm + 16 * w + 4 * g;
    if (H == 4) {
        // packed [r][d][h]: d = 16tt+cl, h = nt>>2 with nt = 4h+tt
#pragma unroll
        for (int tt = 0; tt < 4; ++tt) {
#pragma unroll
            for (int j = 0; j < 4; ++j) {
                int r = r0 + j;
                if (r < M) {
                    u16x4 pv;
#pragma unroll
                    for (int h = 0; h < 4; ++h) pv[h] = f2bf(acc[4 * h + tt][j]);
                    *(u16x4*)&zt[(size_t)r * 256 + (16 * tt + cl) * 4] = pv;
                }
            }
        }
    } else {
#pragma unroll
        for (int nt = 0; nt < NT; ++nt) {
#pragma unroll
            for (int j = 0; j < 4; ++j) {
                int r = r0 + j;
                if (r < M) zt[(size_t)r * N + 16 * nt + cl] = f2bf(acc[nt][j]);
            }
        }
    }
    // fused el/er: head h = cols 64h..64h+63 = tiles 4h..4h+3
#pragma unroll
    for (int h = 0; h < H; ++h) {
        float pl[4] = {0.f, 0.f, 0.f, 0.f};
        float pr[4] = {0.f, 0.f, 0.f, 0.f};
#pragma unroll
        for (int tt = 0; tt < 4; ++tt) {
            int nt = 4 * h + tt;
            float av = al[h * DD + 16 * tt + cl];
            float rv = ar[h * DD + 16 * tt + cl];
#pragma unroll
            for (int j = 0; j < 4; ++j) {
                pl[j] += acc[nt][j] * av;
                pr[j] += acc[nt][j] * rv;
            }
        }
#pragma unroll
        for (int j = 0; j < 4; ++j) {
#pragma unroll
            for (int o = 1; o < 16; o <<= 1) {
                pl[j] += __shfl_xor(pl[j], o);
                pr[j] += __shfl_xor(pr[j], o);
            }
        }
        if (cl == 0) {
#pragma unroll
            for (int j = 0; j < 4; ++j) {
                int r = r0 + j;
                if (r < M) {
                    el[(size_t)r * H + h] = pl[j];
                    er[(size_t)r * H + h] = pr[j];
                }
            }
        }
    }
}

// ---------------- attention: per dst compute c = m + log(den); no per-edge output ----------------
template <int H>
__global__ __launch_bounds__(256) void attn_kernel(const float* __restrict__ el,
                                                   const float* __restrict__ er,
                                                   const int* __restrict__ row_ptr,
                                                   const int* __restrict__ col_src,
                                                   float* __restrict__ cden) {
    int v = blockIdx.x * (blockDim.x >> 6) + (threadIdx.x >> 6);
    int lane = threadIdx.x & 63;
    if (v >= NN) return;
    int start = row_ptr[v], end = row_ptr[v + 1];
    int deg = end - start;
    float erd[H];
#pragma unroll
    for (int h = 0; h < H; ++h) erd[h] = er[(size_t)v * H + h];

    if (deg <= 64) {
        int i = start + lane;
        bool valid = lane < deg;
        int s = col_src[valid ? i : start];
        float e[H];
#pragma unroll
        for (int h = 0; h < H; ++h) {
            float x = el[(size_t)s * H + h] + erd[h];
            x = (x >= 0.f) ? x : NEG_SLOPE * x;
            e[h] = valid ? x : -1e30f;
        }
#pragma unroll
        for (int h = 0; h < H; ++h) {
            float m = wave_max(e[h]);
            float ex = valid ? __expf(e[h] - m) : 0.f;
            float den = wave_sum(ex);
            if (lane == 0) cden[(size_t)v * H + h] = m + logf(den);
        }
    } else {
        float m[H];
#pragma unroll
        for (int h = 0; h < H; ++h) m[h] = -1e30f;
        for (int base = start; base < end; base += 64) {
            int i = base + lane;
            bool valid = i < end;
            int s = col_src[valid ? i : start];
#pragma unroll
            for (int h = 0; h < H; ++h) {
                float x = el[(size_t)s * H + h] + erd[h];
                x = (x >= 0.f) ? x : NEG_SLOPE * x;
                m[h] = fmaxf(m[h], valid ? x : -1e30f);
            }
        }
#pragma unroll
        for (int h = 0; h < H; ++h) m[h] = wave_max(m[h]);
        float den[H];
#pragma unroll
        for (int h = 0; h < H; ++h) den[h] = 0.f;
        for (int base = start; base < end; base += 64) {
            int i = base + lane;
            bool valid = i < end;
            int s = col_src[valid ? i : start];
#pragma unroll
            for (int h = 0; h < H; ++h) {
                float x = el[(size_t)s * H + h] + erd[h];
                x = (x >= 0.f) ? x : NEG_SLOPE * x;
                den[h] += valid ? __expf(x - m[h]) : 0.f;
            }
        }
#pragma unroll
        for (int h = 0; h < H; ++h) {
            float d = wave_sum(den[h]);
            if (lane == 0) cden[(size_t)v * H + h] = m[h] + logf(d);
        }
    }
}

// ---------------- aggregation: alpha recomputed from el/c; bf16 packed z gather ----------------
template <int H, bool SPLIT>
__global__ __launch_bounds__(256) void agg_kernel(const ushort* __restrict__ zt,
                                                  const float* __restrict__ el,
                                                  const float* __restrict__ er,
                                                  const float* __restrict__ cden,
                                                  const int* __restrict__ row_ptr,
                                                  const int* __restrict__ col_src,
                                                  float* __restrict__ outf,
                                                  ushort* __restrict__ ohi,
                                                  ushort* __restrict__ olo) {
    int v = blockIdx.x * (blockDim.x >> 6) + (threadIdx.x >> 6);
    int lane = threadIdx.x & 63;
    if (v >= NN) return;
    int start = row_ptr[v], end = row_ptr[v + 1];
    float erd[H], c[H], acc[H];
#pragma unroll
    for (int h = 0; h < H; ++h) {
        erd[h] = er[(size_t)v * H + h];
        c[h] = cden[(size_t)v * H + h];
        acc[h] = 0.f;
    }

    int i = start;
    if (H == 4) {
        for (; i + 4 <= end; i += 4) {
            int s0 = col_src[i + 0], s1 = col_src[i + 1], s2 = col_src[i + 2], s3 = col_src[i + 3];
            f32x4 e0 = *(const f32x4*)&el[(size_t)s0 * 4];
            f32x4 e1 = *(const f32x4*)&el[(size_t)s1 * 4];
            f32x4 e2 = *(const f32x4*)&el[(size_t)s2 * 4];
            f32x4 e3 = *(const f32x4*)&el[(size_t)s3 * 4];
            u16x4 z0 = *(const u16x4*)&zt[(size_t)s0 * 256 + lane * 4];
            u16x4 z1 = *(const u16x4*)&zt[(size_t)s1 * 256 + lane * 4];
            u16x4 z2 = *(const u16x4*)&zt[(size_t)s2 * 256 + lane * 4];
            u16x4 z3 = *(const u16x4*)&zt[(size_t)s3 * 256 + lane * 4];
#pragma unroll
            for (int h = 0; h < 4; ++h) {
                float x0 = e0[h] + erd[h]; x0 = (x0 >= 0.f) ? x0 : NEG_SLOPE * x0;
                float x1 = e1[h] + erd[h]; x1 = (x1 >= 0.f) ? x1 : NEG_SLOPE * x1;
                float x2 = e2[h] + erd[h]; x2 = (x2 >= 0.f) ? x2 : NEG_SLOPE * x2;
                float x3 = e3[h] + erd[h]; x3 = (x3 >= 0.f) ? x3 : NEG_SLOPE * x3;
                acc[h] += __expf(x0 - c[h]) * bf2f(z0[h]);
                acc[h] += __expf(x1 - c[h]) * bf2f(z1[h]);
                acc[h] += __expf(x2 - c[h]) * bf2f(z2[h]);
                acc[h] += __expf(x3 - c[h]) * bf2f(z3[h]);
            }
        }
        for (; i < end; ++i) {
            int s = col_src[i];
            f32x4 ev = *(const f32x4*)&el[(size_t)s * 4];
            u16x4 zv = *(const u16x4*)&zt[(size_t)s * 256 + lane * 4];
#pragma unroll
            for (int h = 0; h < 4; ++h) {
                float x = ev[h] + erd[h];
                x = (x >= 0.f) ? x : NEG_SLOPE * x;
                acc[h] += __expf(x - c[h]) * bf2f(zv[h]);
            }
        }
    } else {
        for (; i + 4 <= end; i += 4) {
            int s0 = col_src[i + 0], s1 = col_src[i + 1], s2 = col_src[i + 2], s3 = col_src[i + 3];
            float e0 = el[s0], e1 = el[s1], e2 = el[s2], e3 = el[s3];
            ushort z0 = zt[(size_t)s0 * 64 + lane];
            ushort z1 = zt[(size_t)s1 * 64 + lane];
            ushort z2 = zt[(size_t)s2 * 64 + lane];
            ushort z3 = zt[(size_t)s3 * 64 + lane];
            float x0 = e0 + erd[0]; x0 = (x0 >= 0.f) ? x0 : NEG_SLOPE * x0;
            float x1 = e1 + erd[0]; x1 = (x1 >= 0.f) ? x1 : NEG_SLOPE * x1;
            float x2 = e2 + erd[0]; x2 = (x2 >= 0.f) ? x2 : NEG_SLOPE * x2;
            float x3 = e3 + erd[0]; x3 = (x3 >= 0.f) ? x3 : NEG_SLOPE * x3;
            acc[0] += __expf(x0 - c[0]) * bf2f(z0);
            acc[0] += __expf(x1 - c[0]) * bf2f(z1);
            acc[0] += __expf(x2 - c[0]) * bf2f(z2);
            acc[0] += __expf(x3 - c[0]) * bf2f(z3);
        }
        for (; i < end; ++i) {
            int s = col_src[i];
            float x = el[s] + erd[0];
            x = (x >= 0.f) ? x : NEG_SLOPE * x;
            acc[0] += __expf(x - c[0]) * bf2f(zt[(size_t)s * 64 + lane]);
        }
    }

#pragma unroll
    for (int h = 0; h < H; ++h) {
        float r = acc[h];
        r = (r > 0.f) ? r : 0.f;  // fused ReLU
        size_t idx = (size_t)v * H * DD + h * DD + lane;
        if (SPLIT) {
            ushort hb = f2bf(r);
            ohi[idx] = hb;
            olo[idx] = f2bf(r - bf2f(hb));
        } else {
            outf[idx] = r;
        }
    }
}

// ---------------- pooling ----------------
__device__ inline int lower_bound_dev(const int* a, int n, int v) {
    int lo = 0, hi = n;
    while (lo < hi) {
        int mid = (lo + hi) >> 1;
        if (a[mid] < v) lo = mid + 1; else hi = mid;
    }
    return lo;
}

__global__ __launch_bounds__(256) void pool_kernel(const float* __restrict__ x,
                                                   const int* __restrict__ gid,
                                                   float* __restrict__ pooled,
                                                   float* __restrict__ gcnt) {
    int g = blockIdx.x;
    int start = lower_bound_dev(gid, NN, g);
    int end = lower_bound_dev(gid, NN, g + 1);
    int lane = threadIdx.x & 63;
    int w = threadIdx.x >> 6;
    float acc = 0.f;
    for (int i = start + w; i < end; i += 4) acc += x[(size_t)i * DD + lane];
    __shared__ float red[4][DD];
    red[w][lane] = acc;
    __syncthreads();
    if (w == 0) {
        float s = red[0][lane] + red[1][lane] + red[2][lane] + red[3][lane];
        pooled[g * DD + lane] = s;
        if (lane == 0) gcnt[g] = (float)(end - start);
    }
}

// ---------------- head ----------------
__global__ __launch_bounds__(64) void head_kernel(const float* __restrict__ pooled,
                                                  const float* __restrict__ gcnt,
                                                  const float* __restrict__ fc1w,
                                                  const float* __restrict__ fc1b,
                                                  const float* __restrict__ fc2w,
                                                  const float* __restrict__ fc2b,
                                                  float* __restrict__ out) {
    __shared__ float P[GG][DD + 1];
    __shared__ float Y1[GG][DD + 1];
    int g = threadIdx.x;
    float c = fmaxf(gcnt[g], 1.0f);
    for (int k = 0; k < DD; ++k) P[g][k] = pooled[g * DD + k] / c;
    __syncthreads();
    for (int j = 0; j < DD; ++j) {
        float s = fc1b[j];
        for (int k = 0; k < DD; ++k) s += P[g][k] * fc1w[k * DD + j];
        Y1[g][j] = (s > 0.f) ? s : expm1f(s);
    }
    __syncthreads();
    float y2[CC];
    for (int c2 = 0; c2 < CC; ++c2) {
        float s = fc2b[c2];
        for (int j = 0; j < DD; ++j) s += Y1[g][j] * fc2w[j * CC + c2];
        y2[c2] = s;
    }
    for (int c2 = 0; c2 < CC; ++c2) {
        float m = y2[c2];
#pragma unroll
        for (int o = 32; o > 0; o >>= 1) m = fmaxf(m, __shfl_xor(m, o));
        float sexp = __expf(y2[c2] - m);
#pragma unroll
        for (int o = 32; o > 0; o >>= 1) sexp += __shfl_xor(sexp, o);
        out[g * CC + c2] = y2[c2] - m - logf(sexp);
    }
}

// ---------------- launcher ----------------
extern "C" void kernel_launch(void* const* d_in, const int* in_sizes, int n_in,
                              void* d_out, int out_size, void* d_ws, size_t ws_size,
                              hipStream_t stream) {
    const float* h    = (const float*)d_in[0];
    const int* src    = (const int*)d_in[1];
    const int* dst    = (const int*)d_in[2];
    const int* gid    = (const int*)d_in[3];
    const float* W0   = (const float*)d_in[4];
    const float* al0  = (const float*)d_in[5];
    const float* ar0  = (const float*)d_in[6];
    const float* W1   = (const float*)d_in[7];
    const float* al1  = (const float*)d_in[8];
    const float* ar1  = (const float*)d_in[9];
    const float* W2   = (const float*)d_in[10];
    const float* al2  = (const float*)d_in[11];
    const float* ar2  = (const float*)d_in[12];
    const float* W3   = (const float*)d_in[13];
    const float* al3  = (const float*)d_in[14];
    const float* ar3  = (const float*)d_in[15];
    const float* fc1w = (const float*)d_in[16];
    const float* fc1b = (const float*)d_in[17];
    const float* fc2w = (const float*)d_in[18];
    const float* fc2b = (const float*)d_in[19];
    const int E = in_sizes[1];

    char* wsb = (char*)d_ws;
    size_t off = 0;
    auto alloc = [&](size_t bytes) -> void* {
        void* p = wsb + off;
        off = (off + bytes + 255) & ~(size_t)255;
        return p;
    };
    ushort* zt      = (ushort*)alloc((size_t)NN * 256 * 2);  // z bf16, packed [v][d][h] (H=4) / [v][d] (H=1)
    ushort* Ahi     = (ushort*)alloc((size_t)NN * 256 * 2);  // GEMM A input hi
    ushort* Alo     = (ushort*)alloc((size_t)NN * 256 * 2);  // GEMM A input lo
    float*  bufA    = (float*)alloc((size_t)NN * DD * 4);    // layer-3 output (fp32, for pool)
    float*  el      = (float*)alloc((size_t)NN * HH * 4);
    float*  er      = (float*)alloc((size_t)NN * HH * 4);
    float*  cden    = (float*)alloc((size_t)NN * HH * 4);
    int*    counts  = (int*)alloc((size_t)NN * 4);
    int*    row_ptr = (int*)alloc((size_t)(NN + 1) * 4);
    int*    fill    = (int*)alloc((size_t)NN * 4);
    int*    col_src = (int*)alloc((size_t)E * 4);
    float*  pooled  = (float*)alloc((size_t)GG * DD * 4);
    float*  gcnt    = (float*)alloc((size_t)GG * 4);
    ushort* w0h     = (ushort*)alloc((size_t)IN_F * 256 * 2);
    ushort* w0l     = (ushort*)alloc((size_t)IN_F * 256 * 2);
    ushort* w1h     = (ushort*)alloc((size_t)256 * 256 * 2);
    ushort* w1l     = (ushort*)alloc((size_t)256 * 256 * 2);
    ushort* w2h     = (ushort*)alloc((size_t)256 * 256 * 2);
    ushort* w2l     = (ushort*)alloc((size_t)256 * 256 * 2);
    ushort* w3h     = (ushort*)alloc((size_t)256 * 64 * 2);
    ushort* w3l     = (ushort*)alloc((size_t)256 * 64 * 2);

    // ---- CSR build ----
    hipMemsetAsync(counts, 0, (size_t)NN * 4, stream);
    int eg = (E + 255) / 256;
    hist_kernel<<<eg, 256, 0, stream>>>(dst, E, counts);
    scan_kernel<<<1, 1024, 0, stream>>>(counts, row_ptr, fill, NN, E);
    scatter_kernel<<<eg, 256, 0, stream>>>(src, dst, E, fill, col_src);

    // ---- weight + input conversions ----
    wconv_kernel<<<(IN_F * 256 + 255) / 256, 256, 0, stream>>>(W0, IN_F, 256, w0h, w0l);
    wconv_kernel<<<(256 * 256 + 255) / 256, 256, 0, stream>>>(W1, 256, 256, w1h, w1l);
    wconv_kernel<<<(256 * 256 + 255) / 256, 256, 0, stream>>>(W2, 256, 256, w2h, w2l);
    wconv_kernel<<<(256 * 64 + 255) / 256, 256, 0, stream>>>(W3, 256, 64, w3h, w3l);
    hconv_kernel<<<(NN * IN_F + 255) / 256, 256, 0, stream>>>(h, Ahi, Alo, NN * IN_F);

    const int gemmGrid = (NN + 63) / 64;  // 782
    const int waveBlocks = (NN + 3) / 4;  // 12500

    // ---- layer 0 (K=128, N=256, H=4) ----
    gemm_mfma_eler<256, 4><<<gemmGrid, 256, 0, stream>>>(Ahi, Alo, w0h, w0l, zt, al0, ar0, el, er, NN, IN_F);
    attn_kernel<4><<<waveBlocks, 256, 0, stream>>>(el, er, row_ptr, col_src, cden);
    agg_kernel<4, true><<<waveBlocks, 256, 0, stream>>>(zt, el, er, cden, row_ptr, col_src, nullptr, Ahi, Alo);

    // ---- layer 1 ----
    gemm_mfma_eler<256, 4><<<gemmGrid, 256, 0, stream>>>(Ahi, Alo, w1h, w1l, zt, al1, ar1, el, er, NN, 256);
    attn_kernel<4><<<waveBlocks, 256, 0, stream>>>(el, er, row_ptr, col_src, cden);
    agg_kernel<4, true><<<waveBlocks, 256, 0, stream>>>(zt, el, er, cden, row_ptr, col_src, nullptr, Ahi, Alo);

    // ---- layer 2 ----
    gemm_mfma_eler<256, 4><<<gemmGrid, 256, 0, stream>>>(Ahi, Alo, w2h, w2l, zt, al2, ar2, el, er, NN, 256);
    attn_kernel<4><<<waveBlocks, 256, 0, stream>>>(el, er, row_ptr, col_src, cden);
    agg_kernel<4, true><<<waveBlocks, 256, 0, stream>>>(zt, el, er, cden, row_ptr, col_src, nullptr, Ahi, Alo);

    // ---- layer 3 (K=256, N=64, H=1) ----
    gemm_mfma_eler<64, 1><<<gemmGrid, 256, 0, stream>>>(Ahi, Alo, w3h, w3l, zt, al3, ar3, el, er, NN, 256);
    attn_kernel<1><<<waveBlocks, 256, 0, stream>>>(el, er, row_ptr, col_src, cden);
    agg_kernel<1, false><<<waveBlocks, 256, 0, stream>>>(zt, el, er, cden, row_ptr, col_src, bufA, nullptr, nullptr);

    // ---- pooling + head ----
    pool_kernel<<<GG, 256, 0, stream>>>(bufA, gid, pooled, gcnt);
    head_kernel<<<1, 64, 0, stream>>>(pooled, gcnt, fc1w, fc1b, fc2w, fc2b, (float*)d_out);
}

// Round 6
// 748.014 us; speedup vs baseline: 1.9588x; 1.2175x over previous
//
#include <hip/hip_runtime.h>
#include <hip/hip_bf16.h>
#include <math.h>

#define NN 50000
#define IN_F 128
#define DD 64
#define HH 4
#define CC 10
#define GG 64
#define NEG_SLOPE 0.2f

typedef __attribute__((ext_vector_type(8))) short bf16x8;
typedef __attribute__((ext_vector_type(4))) float f32x4;
typedef __attribute__((ext_vector_type(4))) unsigned short u16x4;

__device__ inline ushort f2bf(float f) {
    unsigned u = __float_as_uint(f);
    unsigned r = (u + 0x7fffu + ((u >> 16) & 1u)) >> 16;
    return (ushort)r;
}
__device__ inline float bf2f(ushort b) { return __uint_as_float(((unsigned)b) << 16); }

// ---------------- wave helpers ----------------
__device__ inline float wave_max(float v) {
#pragma unroll
    for (int o = 32; o > 0; o >>= 1) v = fmaxf(v, __shfl_xor(v, o));
    return v;
}
__device__ inline float wave_sum(float v) {
#pragma unroll
    for (int o = 32; o > 0; o >>= 1) v += __shfl_xor(v, o);
    return v;
}

// ---------------- CSR build ----------------
__global__ void hist_kernel(const int* __restrict__ dst, int E, int* __restrict__ counts) {
    int i = blockIdx.x * blockDim.x + threadIdx.x;
    if (i < E) atomicAdd(&counts[dst[i]], 1);
}

// parallel 3-pass scan (replaces the 111us single-block scan)
__global__ __launch_bounds__(256) void scan_blk(const int* __restrict__ counts,
                                                int* __restrict__ excl,
                                                int* __restrict__ bsum, int n) {
    __shared__ int sh[256];
    int t = threadIdx.x;
    int i = blockIdx.x * 256 + t;
    int v = (i < n) ? counts[i] : 0;
    sh[t] = v;
    __syncthreads();
#pragma unroll
    for (int o = 1; o < 256; o <<= 1) {
        int u = (t >= o) ? sh[t - o] : 0;
        __syncthreads();
        sh[t] += u;
        __syncthreads();
    }
    if (i < n) excl[i] = sh[t] - v;
    if (t == 255) bsum[blockIdx.x] = sh[255];
}

__global__ __launch_bounds__(256) void scan_top(int* __restrict__ bsum, int nb) {
    __shared__ int sh[256];
    int t = threadIdx.x;
    int v = (t < nb) ? bsum[t] : 0;
    sh[t] = v;
    __syncthreads();
#pragma unroll
    for (int o = 1; o < 256; o <<= 1) {
        int u = (t >= o) ? sh[t - o] : 0;
        __syncthreads();
        sh[t] += u;
        __syncthreads();
    }
    if (t < nb) bsum[t] = sh[t] - v;  // exclusive
}

__global__ __launch_bounds__(256) void scan_fin(const int* __restrict__ excl,
                                                const int* __restrict__ bsum,
                                                int* __restrict__ row_ptr,
                                                int* __restrict__ fill, int n, int E) {
    int i = blockIdx.x * blockDim.x + threadIdx.x;
    if (i < n) {
        int r = excl[i] + bsum[i >> 8];
        row_ptr[i] = r;
        fill[i] = r;
    }
    if (i == 0) row_ptr[n] = E;
}

__global__ void scatter_kernel(const int* __restrict__ src, const int* __restrict__ dst,
                               int E, int* __restrict__ fill, int* __restrict__ col_src) {
    int i = blockIdx.x * blockDim.x + threadIdx.x;
    if (i < E) {
        int p = atomicAdd(&fill[dst[i]], 1);
        col_src[p] = src[i];
    }
}

// ---------------- fp32 -> bf16 hi/lo split (for layer-0 input h) ----------------
__global__ void hconv_kernel(const float* __restrict__ in, ushort* __restrict__ hi,
                             ushort* __restrict__ lo, int n) {
    int i = blockIdx.x * blockDim.x + threadIdx.x;
    if (i < n) {
        float v = in[i];
        ushort hb = f2bf(v);
        hi[i] = hb;
        lo[i] = f2bf(v - bf2f(hb));
    }
}

// ---------------- W -> transposed, k-blocked, bf16 hi/lo: Wt[kb][n][kk] ----------------
__global__ void wconv_kernel(const float* __restrict__ W, int K, int N,
                             ushort* __restrict__ thi, ushort* __restrict__ tlo) {
    int i = blockIdx.x * blockDim.x + threadIdx.x;
    if (i >= K * N) return;
    int k = i / N, n = i - k * N;
    float v = W[i];
    ushort hb = f2bf(v);
    size_t o = ((size_t)(k >> 5) * N + n) * 32 + (k & 31);
    thi[o] = hb;
    tlo[o] = f2bf(v - bf2f(hb));
}

// ---------------- MFMA GEMM (bf16 split, 64xN blocks) + fused el/er ----------------
template <int N, int H>
__global__ __launch_bounds__(256) void gemm_mfma_eler(
    const ushort* __restrict__ Ahi, const ushort* __restrict__ Alo,
    const ushort* __restrict__ Wthi, const ushort* __restrict__ Wtlo,
    ushort* __restrict__ zt, const float* __restrict__ al, const float* __restrict__ ar,
    float* __restrict__ el, float* __restrict__ er, int M, int K) {
    constexpr int NT = N / 16;
    __shared__ ushort Bh[N][34];  // 68B row stride (odd bank count) -> near-uniform spread
    __shared__ ushort Bl[N][34];
    const int t = threadIdx.x;
    const int w = t >> 6, lane = t & 63;
    const int cl = lane & 15, g = lane >> 4;
    const int bm = blockIdx.x * 64;
    const int arow = bm + 16 * w + cl;
    const bool aval = arow < M;
    const size_t abase = (size_t)arow * K;

    f32x4 acc[NT];
#pragma unroll
    for (int nt = 0; nt < NT; ++nt) acc[nt] = (f32x4){0.f, 0.f, 0.f, 0.f};

    const int nkb = K >> 5;
    for (int kb = 0; kb < nkb; ++kb) {
        __syncthreads();
        if (t < N) {
            const float4* gsh = (const float4*)(Wthi + ((size_t)kb * N + t) * 32);
            const float4* gsl = (const float4*)(Wtlo + ((size_t)kb * N + t) * 32);
#pragma unroll
            for (int q = 0; q < 4; ++q) {
                *(float4*)&Bh[t][q * 8] = gsh[q];
                *(float4*)&Bl[t][q * 8] = gsl[q];
            }
        }
        __syncthreads();
        bf16x8 a_hi = {0, 0, 0, 0, 0, 0, 0, 0};
        bf16x8 a_lo = {0, 0, 0, 0, 0, 0, 0, 0};
        if (aval) {
            a_hi = *(const bf16x8*)(Ahi + abase + kb * 32 + g * 8);
            a_lo = *(const bf16x8*)(Alo + abase + kb * 32 + g * 8);
        }
#pragma unroll
        for (int nt = 0; nt < NT; ++nt) {
            bf16x8 b_hi = *(const bf16x8*)&Bh[16 * nt + cl][g * 8];
            bf16x8 b_lo = *(const bf16x8*)&Bl[16 * nt + cl][g * 8];
            acc[nt] = __builtin_amdgcn_mfma_f32_16x16x32_bf16(a_hi, b_hi, acc[nt], 0, 0, 0);
            acc[nt] = __builtin_amdgcn_mfma_f32_16x16x32_bf16(a_lo, b_hi, acc[nt], 0, 0, 0);
            acc[nt] = __builtin_amdgcn_mfma_f32_16x16x32_bf16(a_hi, b_lo, acc[nt], 0, 0, 0);
        }
    }

    // z store (bf16). Lane holds C[r0+j][16nt+cl], r0 = bm+16w+4g.
    const int r0 = bm + 16 * w + 4 * g;
    if (H == 4) {
#pragma unroll
        for (int tt = 0; tt < 4; ++tt) {
#pragma unroll
            for (int j = 0; j < 4; ++j) {
                int r = r0 + j;
                if (r < M) {
                    u16x4 pv;
#pragma unroll
                    for (int h = 0; h < 4; ++h) pv[h] = f2bf(acc[4 * h + tt][j]);
                    *(u16x4*)&zt[(size_t)r * 256 + (16 * tt + cl) * 4] = pv;
                }
            }
        }
    } else {
#pragma unroll
        for (int nt = 0; nt < NT; ++nt) {
#pragma unroll
            for (int j = 0; j < 4; ++j) {
                int r = r0 + j;
                if (r < M) zt[(size_t)r * N + 16 * nt + cl] = f2bf(acc[nt][j]);
            }
        }
    }
    // fused el/er
#pragma unroll
    for (int h = 0; h < H; ++h) {
        float pl[4] = {0.f, 0.f, 0.f, 0.f};
        float pr[4] = {0.f, 0.f, 0.f, 0.f};
#pragma unroll
        for (int tt = 0; tt < 4; ++tt) {
            int nt = 4 * h + tt;
            float av = al[h * DD + 16 * tt + cl];
            float rv = ar[h * DD + 16 * tt + cl];
#pragma unroll
            for (int j = 0; j < 4; ++j) {
                pl[j] += acc[nt][j] * av;
                pr[j] += acc[nt][j] * rv;
            }
        }
#pragma unroll
        for (int j = 0; j < 4; ++j) {
#pragma unroll
            for (int o = 1; o < 16; o <<= 1) {
                pl[j] += __shfl_xor(pl[j], o);
                pr[j] += __shfl_xor(pr[j], o);
            }
        }
        if (cl == 0) {
#pragma unroll
            for (int j = 0; j < 4; ++j) {
                int r = r0 + j;
                if (r < M) {
                    el[(size_t)r * H + h] = pl[j];
                    er[(size_t)r * H + h] = pr[j];
                }
            }
        }
    }
}

// ---------------- fused attention + aggregation: one wave per dst ----------------
// phase 1 (lane=edge): c = m + log(den) via butterfly reductions (result in all lanes)
// phase 2 (lane=feature): acc += exp(e - c) * z[src]
template <int H, bool SPLIT>
__global__ __launch_bounds__(256) void agg_fused(const ushort* __restrict__ zt,
                                                 const float* __restrict__ el,
                                                 const float* __restrict__ er,
                                                 const int* __restrict__ row_ptr,
                                                 const int* __restrict__ col_src,
                                                 float* __restrict__ outf,
                                                 ushort* __restrict__ ohi,
                                                 ushort* __restrict__ olo) {
    int v = blockIdx.x * (blockDim.x >> 6) + (threadIdx.x >> 6);
    int lane = threadIdx.x & 63;
    if (v >= NN) return;
    int start = row_ptr[v], end = row_ptr[v + 1];
    int deg = end - start;
    float erd[H], c[H];
#pragma unroll
    for (int h = 0; h < H; ++h) erd[h] = er[(size_t)v * H + h];

    // ---- phase 1: softmax constants ----
    if (deg <= 64) {
        bool valid = lane < deg;
        int s = col_src[valid ? start + lane : start];
        float e[H];
#pragma unroll
        for (int h = 0; h < H; ++h) {
            float x = el[(size_t)s * H + h] + erd[h];
            x = (x >= 0.f) ? x : NEG_SLOPE * x;
            e[h] = valid ? x : -1e30f;
        }
#pragma unroll
        for (int h = 0; h < H; ++h) {
            float m = wave_max(e[h]);
            float ex = valid ? __expf(e[h] - m) : 0.f;
            float den = wave_sum(ex);
            c[h] = m + logf(den);
        }
    } else {
        float m[H];
#pragma unroll
        for (int h = 0; h < H; ++h) m[h] = -1e30f;
        for (int base = start; base < end; base += 64) {
            int i = base + lane;
            bool valid = i < end;
            int s = col_src[valid ? i : start];
#pragma unroll
            for (int h = 0; h < H; ++h) {
                float x = el[(size_t)s * H + h] + erd[h];
                x = (x >= 0.f) ? x : NEG_SLOPE * x;
                m[h] = fmaxf(m[h], valid ? x : -1e30f);
            }
        }
#pragma unroll
        for (int h = 0; h < H; ++h) m[h] = wave_max(m[h]);
        float den[H];
#pragma unroll
        for (int h = 0; h < H; ++h) den[h] = 0.f;
        for (int base = start; base < end; base += 64) {
            int i = base + lane;
            bool valid = i < end;
            int s = col_src[valid ? i : start];
#pragma unroll
            for (int h = 0; h < H; ++h) {
                float x = el[(size_t)s * H + h] + erd[h];
                x = (x >= 0.f) ? x : NEG_SLOPE * x;
                den[h] += valid ? __expf(x - m[h]) : 0.f;
            }
        }
#pragma unroll
        for (int h = 0; h < H; ++h) c[h] = m[h] + logf(wave_sum(den[h]));
    }

    // ---- phase 2: weighted aggregation (lane = feature) ----
    float acc[H];
#pragma unroll
    for (int h = 0; h < H; ++h) acc[h] = 0.f;

    int i = start;
    if (H == 4) {
        for (; i + 4 <= end; i += 4) {
            int s0 = col_src[i + 0], s1 = col_src[i + 1], s2 = col_src[i + 2], s3 = col_src[i + 3];
            f32x4 e0 = *(const f32x4*)&el[(size_t)s0 * 4];
            f32x4 e1 = *(const f32x4*)&el[(size_t)s1 * 4];
            f32x4 e2 = *(const f32x4*)&el[(size_t)s2 * 4];
            f32x4 e3 = *(const f32x4*)&el[(size_t)s3 * 4];
            u16x4 z0 = *(const u16x4*)&zt[(size_t)s0 * 256 + lane * 4];
            u16x4 z1 = *(const u16x4*)&zt[(size_t)s1 * 256 + lane * 4];
            u16x4 z2 = *(const u16x4*)&zt[(size_t)s2 * 256 + lane * 4];
            u16x4 z3 = *(const u16x4*)&zt[(size_t)s3 * 256 + lane * 4];
#pragma unroll
            for (int h = 0; h < 4; ++h) {
                float x0 = e0[h] + erd[h]; x0 = (x0 >= 0.f) ? x0 : NEG_SLOPE * x0;
                float x1 = e1[h] + erd[h]; x1 = (x1 >= 0.f) ? x1 : NEG_SLOPE * x1;
                float x2 = e2[h] + erd[h]; x2 = (x2 >= 0.f) ? x2 : NEG_SLOPE * x2;
                float x3 = e3[h] + erd[h]; x3 = (x3 >= 0.f) ? x3 : NEG_SLOPE * x3;
                acc[h] += __expf(x0 - c[h]) * bf2f(z0[h]);
                acc[h] += __expf(x1 - c[h]) * bf2f(z1[h]);
                acc[h] += __expf(x2 - c[h]) * bf2f(z2[h]);
                acc[h] += __expf(x3 - c[h]) * bf2f(z3[h]);
            }
        }
        for (; i < end; ++i) {
            int s = col_src[i];
            f32x4 ev = *(const f32x4*)&el[(size_t)s * 4];
            u16x4 zv = *(const u16x4*)&zt[(size_t)s * 256 + lane * 4];
#pragma unroll
            for (int h = 0; h < 4; ++h) {
                float x = ev[h] + erd[h];
                x = (x >= 0.f) ? x : NEG_SLOPE * x;
                acc[h] += __expf(x - c[h]) * bf2f(zv[h]);
            }
        }
    } else {
        for (; i + 4 <= end; i += 4) {
            int s0 = col_src[i + 0], s1 = col_src[i + 1], s2 = col_src[i + 2], s3 = col_src[i + 3];
            float e0 = el[s0], e1 = el[s1], e2 = el[s2], e3 = el[s3];
            ushort z0 = zt[(size_t)s0 * 64 + lane];
            ushort z1 = zt[(size_t)s1 * 64 + lane];
            ushort z2 = zt[(size_t)s2 * 64 + lane];
            ushort z3 = zt[(size_t)s3 * 64 + lane];
            float x0 = e0 + erd[0]; x0 = (x0 >= 0.f) ? x0 : NEG_SLOPE * x0;
            float x1 = e1 + erd[0]; x1 = (x1 >= 0.f) ? x1 : NEG_SLOPE * x1;
            float x2 = e2 + erd[0]; x2 = (x2 >= 0.f) ? x2 : NEG_SLOPE * x2;
            float x3 = e3 + erd[0]; x3 = (x3 >= 0.f) ? x3 : NEG_SLOPE * x3;
            acc[0] += __expf(x0 - c[0]) * bf2f(z0);
            acc[0] += __expf(x1 - c[0]) * bf2f(z1);
            acc[0] += __expf(x2 - c[0]) * bf2f(z2);
            acc[0] += __expf(x3 - c[0]) * bf2f(z3);
        }
        for (; i < end; ++i) {
            int s = col_src[i];
            float x = el[s] + erd[0];
            x = (x >= 0.f) ? x : NEG_SLOPE * x;
            acc[0] += __expf(x - c[0]) * bf2f(zt[(size_t)s * 64 + lane]);
        }
    }

#pragma unroll
    for (int h = 0; h < H; ++h) {
        float r = acc[h];
        r = (r > 0.f) ? r : 0.f;  // fused ReLU
        size_t idx = (size_t)v * H * DD + h * DD + lane;
        if (SPLIT) {
            ushort hb = f2bf(r);
            ohi[idx] = hb;
            olo[idx] = f2bf(r - bf2f(hb));
        } else {
            outf[idx] = r;
        }
    }
}

// ---------------- pooling ----------------
__device__ inline int lower_bound_dev(const int* a, int n, int v) {
    int lo = 0, hi = n;
    while (lo < hi) {
        int mid = (lo + hi) >> 1;
        if (a[mid] < v) lo = mid + 1; else hi = mid;
    }
    return lo;
}

__global__ __launch_bounds__(256) void pool_kernel(const float* __restrict__ x,
                                                   const int* __restrict__ gid,
                                                   float* __restrict__ pooled,
                                                   float* __restrict__ gcnt) {
    int g = blockIdx.x;
    int start = lower_bound_dev(gid, NN, g);
    int end = lower_bound_dev(gid, NN, g + 1);
    int lane = threadIdx.x & 63;
    int w = threadIdx.x >> 6;
    float acc = 0.f;
    for (int i = start + w; i < end; i += 4) acc += x[(size_t)i * DD + lane];
    __shared__ float red[4][DD];
    red[w][lane] = acc;
    __syncthreads();
    if (w == 0) {
        float s = red[0][lane] + red[1][lane] + red[2][lane] + red[3][lane];
        pooled[g * DD + lane] = s;
        if (lane == 0) gcnt[g] = (float)(end - start);
    }
}

// ---------------- head ----------------
__global__ __launch_bounds__(64) void head_kernel(const float* __restrict__ pooled,
                                                  const float* __restrict__ gcnt,
                                                  const float* __restrict__ fc1w,
                                                  const float* __restrict__ fc1b,
                                                  const float* __restrict__ fc2w,
                                                  const float* __restrict__ fc2b,
                                                  float* __restrict__ out) {
    __shared__ float P[GG][DD + 1];
    __shared__ float Y1[GG][DD + 1];
    int g = threadIdx.x;
    float c = fmaxf(gcnt[g], 1.0f);
    for (int k = 0; k < DD; ++k) P[g][k] = pooled[g * DD + k] / c;
    __syncthreads();
    for (int j = 0; j < DD; ++j) {
        float s = fc1b[j];
        for (int k = 0; k < DD; ++k) s += P[g][k] * fc1w[k * DD + j];
        Y1[g][j] = (s > 0.f) ? s : expm1f(s);
    }
    __syncthreads();
    float y2[CC];
    for (int c2 = 0; c2 < CC; ++c2) {
        float s = fc2b[c2];
        for (int j = 0; j < DD; ++j) s += Y1[g][j] * fc2w[j * CC + c2];
        y2[c2] = s;
    }
    for (int c2 = 0; c2 < CC; ++c2) {
        float m = y2[c2];
#pragma unroll
        for (int o = 32; o > 0; o >>= 1) m = fmaxf(m, __shfl_xor(m, o));
        float sexp = __expf(y2[c2] - m);
#pragma unroll
        for (int o = 32; o > 0; o >>= 1) sexp += __shfl_xor(sexp, o);
        out[g * CC + c2] = y2[c2] - m - logf(sexp);
    }
}

// ---------------- launcher ----------------
extern "C" void kernel_launch(void* const* d_in, const int* in_sizes, int n_in,
                              void* d_out, int out_size, void* d_ws, size_t ws_size,
                              hipStream_t stream) {
    const float* h    = (const float*)d_in[0];
    const int* src    = (const int*)d_in[1];
    const int* dst    = (const int*)d_in[2];
    const int* gid    = (const int*)d_in[3];
    const float* W0   = (const float*)d_in[4];
    const float* al0  = (const float*)d_in[5];
    const float* ar0  = (const float*)d_in[6];
    const float* W1   = (const float*)d_in[7];
    const float* al1  = (const float*)d_in[8];
    const float* ar1  = (const float*)d_in[9];
    const float* W2   = (const float*)d_in[10];
    const float* al2  = (const float*)d_in[11];
    const float* ar2  = (const float*)d_in[12];
    const float* W3   = (const float*)d_in[13];
    const float* al3  = (const float*)d_in[14];
    const float* ar3  = (const float*)d_in[15];
    const float* fc1w = (const float*)d_in[16];
    const float* fc1b = (const float*)d_in[17];
    const float* fc2w = (const float*)d_in[18];
    const float* fc2b = (const float*)d_in[19];
    const int E = in_sizes[1];

    char* wsb = (char*)d_ws;
    size_t off = 0;
    auto alloc = [&](size_t bytes) -> void* {
        void* p = wsb + off;
        off = (off + bytes + 255) & ~(size_t)255;
        return p;
    };
    ushort* zt      = (ushort*)alloc((size_t)NN * 256 * 2);  // z bf16, packed [v][d][h] (H=4) / [v][d] (H=1)
    ushort* Ahi     = (ushort*)alloc((size_t)NN * 256 * 2);
    ushort* Alo     = (ushort*)alloc((size_t)NN * 256 * 2);
    float*  bufA    = (float*)alloc((size_t)NN * DD * 4);
    float*  el      = (float*)alloc((size_t)NN * HH * 4);
    float*  er      = (float*)alloc((size_t)NN * HH * 4);
    int*    counts  = (int*)alloc((size_t)NN * 4);
    int*    row_ptr = (int*)alloc((size_t)(NN + 1) * 4);
    int*    fill    = (int*)alloc((size_t)NN * 4);
    int*    excl    = (int*)alloc((size_t)NN * 4);
    int*    bsum    = (int*)alloc((size_t)256 * 4);
    int*    col_src = (int*)alloc((size_t)E * 4);
    float*  pooled  = (float*)alloc((size_t)GG * DD * 4);
    float*  gcnt    = (float*)alloc((size_t)GG * 4);
    ushort* w0h     = (ushort*)alloc((size_t)IN_F * 256 * 2);
    ushort* w0l     = (ushort*)alloc((size_t)IN_F * 256 * 2);
    ushort* w1h     = (ushort*)alloc((size_t)256 * 256 * 2);
    ushort* w1l     = (ushort*)alloc((size_t)256 * 256 * 2);
    ushort* w2h     = (ushort*)alloc((size_t)256 * 256 * 2);
    ushort* w2l     = (ushort*)alloc((size_t)256 * 256 * 2);
    ushort* w3h     = (ushort*)alloc((size_t)256 * 64 * 2);
    ushort* w3l     = (ushort*)alloc((size_t)256 * 64 * 2);

    // ---- CSR build ----
    hipMemsetAsync(counts, 0, (size_t)NN * 4, stream);
    int eg = (E + 255) / 256;
    const int nScanBlk = (NN + 255) / 256;  // 196
    hist_kernel<<<eg, 256, 0, stream>>>(dst, E, counts);
    scan_blk<<<nScanBlk, 256, 0, stream>>>(counts, excl, bsum, NN);
    scan_top<<<1, 256, 0, stream>>>(bsum, nScanBlk);
    scan_fin<<<nScanBlk, 256, 0, stream>>>(excl, bsum, row_ptr, fill, NN, E);
    scatter_kernel<<<eg, 256, 0, stream>>>(src, dst, E, fill, col_src);

    // ---- weight + input conversions ----
    wconv_kernel<<<(IN_F * 256 + 255) / 256, 256, 0, stream>>>(W0, IN_F, 256, w0h, w0l);
    wconv_kernel<<<(256 * 256 + 255) / 256, 256, 0, stream>>>(W1, 256, 256, w1h, w1l);
    wconv_kernel<<<(256 * 256 + 255) / 256, 256, 0, stream>>>(W2, 256, 256, w2h, w2l);
    wconv_kernel<<<(256 * 64 + 255) / 256, 256, 0, stream>>>(W3, 256, 64, w3h, w3l);
    hconv_kernel<<<(NN * IN_F + 255) / 256, 256, 0, stream>>>(h, Ahi, Alo, NN * IN_F);

    const int gemmGrid = (NN + 63) / 64;  // 782
    const int waveBlocks = (NN + 3) / 4;  // 12500

    // ---- layer 0 (K=128, N=256, H=4) ----
    gemm_mfma_eler<256, 4><<<gemmGrid, 256, 0, stream>>>(Ahi, Alo, w0h, w0l, zt, al0, ar0, el, er, NN, IN_F);
    agg_fused<4, true><<<waveBlocks, 256, 0, stream>>>(zt, el, er, row_ptr, col_src, nullptr, Ahi, Alo);

    // ---- layer 1 ----
    gemm_mfma_eler<256, 4><<<gemmGrid, 256, 0, stream>>>(Ahi, Alo, w1h, w1l, zt, al1, ar1, el, er, NN, 256);
    agg_fused<4, true><<<waveBlocks, 256, 0, stream>>>(zt, el, er, row_ptr, col_src, nullptr, Ahi, Alo);

    // ---- layer 2 ----
    gemm_mfma_eler<256, 4><<<gemmGrid, 256, 0, stream>>>(Ahi, Alo, w2h, w2l, zt, al2, ar2, el, er, NN, 256);
    agg_fused<4, true><<<waveBlocks, 256, 0, stream>>>(zt, el, er, row_ptr, col_src, nullptr, Ahi, Alo);

    // ---- layer 3 (K=256, N=64, H=1) ----
    gemm_mfma_eler<64, 1><<<gemmGrid, 256, 0, stream>>>(Ahi, Alo, w3h, w3l, zt, al3, ar3, el, er, NN, 256);
    agg_fused<1, false><<<waveBlocks, 256, 0, stream>>>(zt, el, er, row_ptr, col_src, bufA, nullptr, nullptr);

    // ---- pooling + head ----
    pool_kernel<<<GG, 256, 0, stream>>>(bufA, gid, pooled, gcnt);
    head_kernel<<<1, 64, 0, stream>>>(pooled, gcnt, fc1w, fc1b, fc2w, fc2b, (float*)d_out);
}

// Round 7
// 683.556 us; speedup vs baseline: 2.1435x; 1.0943x over previous
//
#include <hip/hip_runtime.h>
#include <hip/hip_bf16.h>
#include <math.h>

#define NN 50000
#define IN_F 128
#define DD 64
#define HH 4
#define CC 10
#define GG 64
#define NEG_SLOPE 0.2f

typedef __attribute__((ext_vector_type(8))) short bf16x8;
typedef __attribute__((ext_vector_type(4))) float f32x4;
typedef __attribute__((ext_vector_type(4))) unsigned short u16x4;

__device__ inline ushort f2bf(float f) {
    unsigned u = __float_as_uint(f);
    unsigned r = (u + 0x7fffu + ((u >> 16) & 1u)) >> 16;
    return (ushort)r;
}
__device__ inline float bf2f(ushort b) { return __uint_as_float(((unsigned)b) << 16); }

// ---------------- wave helpers ----------------
__device__ inline float wave_max(float v) {
#pragma unroll
    for (int o = 32; o > 0; o >>= 1) v = fmaxf(v, __shfl_xor(v, o));
    return v;
}
__device__ inline float wave_sum(float v) {
#pragma unroll
    for (int o = 32; o > 0; o >>= 1) v += __shfl_xor(v, o);
    return v;
}

// ---------------- CSR build ----------------
__global__ void hist_kernel(const int* __restrict__ dst, int E, int* __restrict__ counts) {
    int i = blockIdx.x * blockDim.x + threadIdx.x;
    if (i < E) atomicAdd(&counts[dst[i]], 1);
}

__global__ __launch_bounds__(256) void scan_blk(const int* __restrict__ counts,
                                                int* __restrict__ excl,
                                                int* __restrict__ bsum, int n) {
    __shared__ int sh[256];
    int t = threadIdx.x;
    int i = blockIdx.x * 256 + t;
    int v = (i < n) ? counts[i] : 0;
    sh[t] = v;
    __syncthreads();
#pragma unroll
    for (int o = 1; o < 256; o <<= 1) {
        int u = (t >= o) ? sh[t - o] : 0;
        __syncthreads();
        sh[t] += u;
        __syncthreads();
    }
    if (i < n) excl[i] = sh[t] - v;
    if (t == 255) bsum[blockIdx.x] = sh[255];
}

__global__ __launch_bounds__(256) void scan_top(int* __restrict__ bsum, int nb) {
    __shared__ int sh[256];
    int t = threadIdx.x;
    int v = (t < nb) ? bsum[t] : 0;
    sh[t] = v;
    __syncthreads();
#pragma unroll
    for (int o = 1; o < 256; o <<= 1) {
        int u = (t >= o) ? sh[t - o] : 0;
        __syncthreads();
        sh[t] += u;
        __syncthreads();
    }
    if (t < nb) bsum[t] = sh[t] - v;  // exclusive
}

__global__ __launch_bounds__(256) void scan_fin(const int* __restrict__ excl,
                                                const int* __restrict__ bsum,
                                                int* __restrict__ row_ptr,
                                                int* __restrict__ fill, int n, int E) {
    int i = blockIdx.x * blockDim.x + threadIdx.x;
    if (i < n) {
        int r = excl[i] + bsum[i >> 8];
        row_ptr[i] = r;
        fill[i] = r;
    }
    if (i == 0) row_ptr[n] = E;
}

__global__ void scatter_kernel(const int* __restrict__ src, const int* __restrict__ dst,
                               int E, int* __restrict__ fill, int* __restrict__ col_src) {
    int i = blockIdx.x * blockDim.x + threadIdx.x;
    if (i < E) {
        int p = atomicAdd(&fill[dst[i]], 1);
        col_src[p] = src[i];
    }
}

// ---------------- fp32 -> bf16 hi/lo split (for layer-0 input h) ----------------
__global__ void hconv_kernel(const float* __restrict__ in, ushort* __restrict__ hi,
                             ushort* __restrict__ lo, int n) {
    int i = blockIdx.x * blockDim.x + threadIdx.x;
    if (i < n) {
        float v = in[i];
        ushort hb = f2bf(v);
        hi[i] = hb;
        lo[i] = f2bf(v - bf2f(hb));
    }
}

// ---------------- W -> transposed, k-blocked, bf16 hi/lo: Wt[kb][n][kk] ----------------
__global__ void wconv_kernel(const float* __restrict__ W, int K, int N,
                             ushort* __restrict__ thi, ushort* __restrict__ tlo) {
    int i = blockIdx.x * blockDim.x + threadIdx.x;
    if (i >= K * N) return;
    int k = i / N, n = i - k * N;
    float v = W[i];
    ushort hb = f2bf(v);
    size_t o = ((size_t)(k >> 5) * N + n) * 32 + (k & 31);
    thi[o] = hb;
    tlo[o] = f2bf(v - bf2f(hb));
}

// ---------------- MFMA GEMM (bf16 split, 64xN blocks) + fused el/er ----------------
template <int N, int H>
__global__ __launch_bounds__(256) void gemm_mfma_eler(
    const ushort* __restrict__ Ahi, const ushort* __restrict__ Alo,
    const ushort* __restrict__ Wthi, const ushort* __restrict__ Wtlo,
    ushort* __restrict__ zt, const float* __restrict__ al, const float* __restrict__ ar,
    float* __restrict__ el, float* __restrict__ er, int M, int K) {
    constexpr int NT = N / 16;
    __shared__ ushort Bh[N][34];  // 68B row stride (odd bank count) -> near-uniform spread
    __shared__ ushort Bl[N][34];
    const int t = threadIdx.x;
    const int w = t >> 6, lane = t & 63;
    const int cl = lane & 15, g = lane >> 4;
    const int bm = blockIdx.x * 64;
    const int arow = bm + 16 * w + cl;
    const bool aval = arow < M;
    const size_t abase = (size_t)arow * K;

    f32x4 acc[NT];
#pragma unroll
    for (int nt = 0; nt < NT; ++nt) acc[nt] = (f32x4){0.f, 0.f, 0.f, 0.f};

    const int nkb = K >> 5;
    for (int kb = 0; kb < nkb; ++kb) {
        __syncthreads();
        if (t < N) {
            const float4* gsh = (const float4*)(Wthi + ((size_t)kb * N + t) * 32);
            const float4* gsl = (const float4*)(Wtlo + ((size_t)kb * N + t) * 32);
#pragma unroll
            for (int q = 0; q < 4; ++q) {
                *(float4*)&Bh[t][q * 8] = gsh[q];
                *(float4*)&Bl[t][q * 8] = gsl[q];
            }
        }
        __syncthreads();
        bf16x8 a_hi = {0, 0, 0, 0, 0, 0, 0, 0};
        bf16x8 a_lo = {0, 0, 0, 0, 0, 0, 0, 0};
        if (aval) {
            a_hi = *(const bf16x8*)(Ahi + abase + kb * 32 + g * 8);
            a_lo = *(const bf16x8*)(Alo + abase + kb * 32 + g * 8);
        }
#pragma unroll
        for (int nt = 0; nt < NT; ++nt) {
            bf16x8 b_hi = *(const bf16x8*)&Bh[16 * nt + cl][g * 8];
            bf16x8 b_lo = *(const bf16x8*)&Bl[16 * nt + cl][g * 8];
            acc[nt] = __builtin_amdgcn_mfma_f32_16x16x32_bf16(a_hi, b_hi, acc[nt], 0, 0, 0);
            acc[nt] = __builtin_amdgcn_mfma_f32_16x16x32_bf16(a_lo, b_hi, acc[nt], 0, 0, 0);
            acc[nt] = __builtin_amdgcn_mfma_f32_16x16x32_bf16(a_hi, b_lo, acc[nt], 0, 0, 0);
        }
    }

    // z store (bf16). Lane holds C[r0+j][16nt+cl], r0 = bm+16w+4g.
    const int r0 = bm + 16 * w + 4 * g;
    if (H == 4) {
#pragma unroll
        for (int tt = 0; tt < 4; ++tt) {
#pragma unroll
            for (int j = 0; j < 4; ++j) {
                int r = r0 + j;
                if (r < M) {
                    u16x4 pv;
#pragma unroll
                    for (int h = 0; h < 4; ++h) pv[h] = f2bf(acc[4 * h + tt][j]);
                    *(u16x4*)&zt[(size_t)r * 256 + (16 * tt + cl) * 4] = pv;
                }
            }
        }
    } else {
#pragma unroll
        for (int nt = 0; nt < NT; ++nt) {
#pragma unroll
            for (int j = 0; j < 4; ++j) {
                int r = r0 + j;
                if (r < M) zt[(size_t)r * N + 16 * nt + cl] = f2bf(acc[nt][j]);
            }
        }
    }
    // fused el/er
#pragma unroll
    for (int h = 0; h < H; ++h) {
        float pl[4] = {0.f, 0.f, 0.f, 0.f};
        float pr[4] = {0.f, 0.f, 0.f, 0.f};
#pragma unroll
        for (int tt = 0; tt < 4; ++tt) {
            int nt = 4 * h + tt;
            float av = al[h * DD + 16 * tt + cl];
            float rv = ar[h * DD + 16 * tt + cl];
#pragma unroll
            for (int j = 0; j < 4; ++j) {
                pl[j] += acc[nt][j] * av;
                pr[j] += acc[nt][j] * rv;
            }
        }
#pragma unroll
        for (int j = 0; j < 4; ++j) {
#pragma unroll
            for (int o = 1; o < 16; o <<= 1) {
                pl[j] += __shfl_xor(pl[j], o);
                pr[j] += __shfl_xor(pr[j], o);
            }
        }
        if (cl == 0) {
#pragma unroll
            for (int j = 0; j < 4; ++j) {
                int r = r0 + j;
                if (r < M) {
                    el[(size_t)r * H + h] = pl[j];
                    er[(size_t)r * H + h] = pr[j];
                }
            }
        }
    }
}

// ---------------- fused attention + aggregation: one wave per dst ----------------
// phase A (lane=edge): alpha = exp(e-m)/den computed ONCE per edge, stored to per-wave LDS
// phase B (lane=feature): acc[h] += alpha[j][h] * z[src_j]  (LDS broadcast reads)
template <int H, bool SPLIT>
__global__ __launch_bounds__(256) void agg_fused(const ushort* __restrict__ zt,
                                                 const float* __restrict__ el,
                                                 const float* __restrict__ er,
                                                 const int* __restrict__ row_ptr,
                                                 const int* __restrict__ col_src,
                                                 float* __restrict__ outf,
                                                 ushort* __restrict__ ohi,
                                                 ushort* __restrict__ olo) {
    __shared__ float alf[4][64][H];  // per-wave alpha slab
    __shared__ int als[4][64];       // per-wave src ids
    const int wid = threadIdx.x >> 6;
    const int lane = threadIdx.x & 63;
    int v = blockIdx.x * 4 + wid;
    if (v >= NN) return;
    int start = row_ptr[v], end = row_ptr[v + 1];
    int deg = end - start;
    float erd[H], acc[H];
#pragma unroll
    for (int h = 0; h < H; ++h) {
        erd[h] = er[(size_t)v * H + h];
        acc[h] = 0.f;
    }

    // phase-B inner loop over a chunk of edges resident in LDS
    auto agg_chunk = [&](int cnt) {
        int j = 0;
        for (; j + 4 <= cnt; j += 4) {
            int s0 = als[wid][j + 0], s1 = als[wid][j + 1];
            int s2 = als[wid][j + 2], s3 = als[wid][j + 3];
            if (H == 4) {
                f32x4 a0 = *(const f32x4*)&alf[wid][j + 0][0];
                f32x4 a1 = *(const f32x4*)&alf[wid][j + 1][0];
                f32x4 a2 = *(const f32x4*)&alf[wid][j + 2][0];
                f32x4 a3 = *(const f32x4*)&alf[wid][j + 3][0];
                u16x4 z0 = *(const u16x4*)&zt[(size_t)s0 * 256 + lane * 4];
                u16x4 z1 = *(const u16x4*)&zt[(size_t)s1 * 256 + lane * 4];
                u16x4 z2 = *(const u16x4*)&zt[(size_t)s2 * 256 + lane * 4];
                u16x4 z3 = *(const u16x4*)&zt[(size_t)s3 * 256 + lane * 4];
#pragma unroll
                for (int h = 0; h < 4; ++h) {
                    acc[h] += a0[h] * bf2f(z0[h]);
                    acc[h] += a1[h] * bf2f(z1[h]);
                    acc[h] += a2[h] * bf2f(z2[h]);
                    acc[h] += a3[h] * bf2f(z3[h]);
                }
            } else {
                float a0 = alf[wid][j + 0][0], a1 = alf[wid][j + 1][0];
                float a2 = alf[wid][j + 2][0], a3 = alf[wid][j + 3][0];
                ushort z0 = zt[(size_t)s0 * 64 + lane];
                ushort z1 = zt[(size_t)s1 * 64 + lane];
                ushort z2 = zt[(size_t)s2 * 64 + lane];
                ushort z3 = zt[(size_t)s3 * 64 + lane];
                acc[0] += a0 * bf2f(z0);
                acc[0] += a1 * bf2f(z1);
                acc[0] += a2 * bf2f(z2);
                acc[0] += a3 * bf2f(z3);
            }
        }
        for (; j < cnt; ++j) {
            int s = als[wid][j];
            if (H == 4) {
                f32x4 a = *(const f32x4*)&alf[wid][j][0];
                u16x4 z = *(const u16x4*)&zt[(size_t)s * 256 + lane * 4];
#pragma unroll
                for (int h = 0; h < 4; ++h) acc[h] += a[h] * bf2f(z[h]);
            } else {
                acc[0] += alf[wid][j][0] * bf2f(zt[(size_t)s * 64 + lane]);
            }
        }
    };

    if (deg <= 64) {
        bool valid = lane < deg;
        int s = col_src[valid ? start + lane : start];
        als[wid][lane] = s;
        float e[H];
        if (H == 4) {
            f32x4 ev = *(const f32x4*)&el[(size_t)s * 4];
#pragma unroll
            for (int h = 0; h < 4; ++h) {
                float x = ev[h] + erd[h];
                x = (x >= 0.f) ? x : NEG_SLOPE * x;
                e[h] = valid ? x : -1e30f;
            }
        } else {
            float x = el[s] + erd[0];
            x = (x >= 0.f) ? x : NEG_SLOPE * x;
            e[0] = valid ? x : -1e30f;
        }
#pragma unroll
        for (int h = 0; h < H; ++h) {
            float m = wave_max(e[h]);
            float ex = valid ? __expf(e[h] - m) : 0.f;
            float den = wave_sum(ex);
            alf[wid][lane][h] = ex * (1.f / den);
        }
        __builtin_amdgcn_wave_barrier();
        agg_chunk(deg);
    } else {
        // rare path: two passes for m/den, then chunked alpha->LDS + aggregate
        float m[H];
#pragma unroll
        for (int h = 0; h < H; ++h) m[h] = -1e30f;
        for (int base = start; base < end; base += 64) {
            int i = base + lane;
            bool valid = i < end;
            int s = col_src[valid ? i : start];
#pragma unroll
            for (int h = 0; h < H; ++h) {
                float x = el[(size_t)s * H + h] + erd[h];
                x = (x >= 0.f) ? x : NEG_SLOPE * x;
                m[h] = fmaxf(m[h], valid ? x : -1e30f);
            }
        }
        float den[H];
#pragma unroll
        for (int h = 0; h < H; ++h) {
            m[h] = wave_max(m[h]);
            den[h] = 0.f;
        }
        for (int base = start; base < end; base += 64) {
            int i = base + lane;
            bool valid = i < end;
            int s = col_src[valid ? i : start];
#pragma unroll
            for (int h = 0; h < H; ++h) {
                float x = el[(size_t)s * H + h] + erd[h];
                x = (x >= 0.f) ? x : NEG_SLOPE * x;
                den[h] += valid ? __expf(x - m[h]) : 0.f;
            }
        }
        float inv[H];
#pragma unroll
        for (int h = 0; h < H; ++h) inv[h] = 1.f / wave_sum(den[h]);
        for (int base = start; base < end; base += 64) {
            int i = base + lane;
            bool valid = i < end;
            int s = col_src[valid ? i : start];
            als[wid][lane] = s;
#pragma unroll
            for (int h = 0; h < H; ++h) {
                float x = el[(size_t)s * H + h] + erd[h];
                x = (x >= 0.f) ? x : NEG_SLOPE * x;
                alf[wid][lane][h] = valid ? __expf(x - m[h]) * inv[h] : 0.f;
            }
            __builtin_amdgcn_wave_barrier();
            int cnt = min(64, end - base);
            agg_chunk(cnt);
            __builtin_amdgcn_wave_barrier();
        }
    }

#pragma unroll
    for (int h = 0; h < H; ++h) {
        float r = acc[h];
        r = (r > 0.f) ? r : 0.f;  // fused ReLU
        size_t idx = (size_t)v * H * DD + h * DD + lane;
        if (SPLIT) {
            ushort hb = f2bf(r);
            ohi[idx] = hb;
            olo[idx] = f2bf(r - bf2f(hb));
        } else {
            outf[idx] = r;
        }
    }
}

// ---------------- pooling ----------------
__device__ inline int lower_bound_dev(const int* a, int n, int v) {
    int lo = 0, hi = n;
    while (lo < hi) {
        int mid = (lo + hi) >> 1;
        if (a[mid] < v) lo = mid + 1; else hi = mid;
    }
    return lo;
}

__global__ __launch_bounds__(256) void pool_kernel(const float* __restrict__ x,
                                                   const int* __restrict__ gid,
                                                   float* __restrict__ pooled,
                                                   float* __restrict__ gcnt) {
    int g = blockIdx.x;
    int start = lower_bound_dev(gid, NN, g);
    int end = lower_bound_dev(gid, NN, g + 1);
    int lane = threadIdx.x & 63;
    int w = threadIdx.x >> 6;
    float acc = 0.f;
    for (int i = start + w; i < end; i += 4) acc += x[(size_t)i * DD + lane];
    __shared__ float red[4][DD];
    red[w][lane] = acc;
    __syncthreads();
    if (w == 0) {
        float s = red[0][lane] + red[1][lane] + red[2][lane] + red[3][lane];
        pooled[g * DD + lane] = s;
        if (lane == 0) gcnt[g] = (float)(end - start);
    }
}

// ---------------- head ----------------
__global__ __launch_bounds__(64) void head_kernel(const float* __restrict__ pooled,
                                                  const float* __restrict__ gcnt,
                                                  const float* __restrict__ fc1w,
                                                  const float* __restrict__ fc1b,
                                                  const float* __restrict__ fc2w,
                                                  const float* __restrict__ fc2b,
                                                  float* __restrict__ out) {
    __shared__ float P[GG][DD + 1];
    __shared__ float Y1[GG][DD + 1];
    int g = threadIdx.x;
    float c = fmaxf(gcnt[g], 1.0f);
    for (int k = 0; k < DD; ++k) P[g][k] = pooled[g * DD + k] / c;
    __syncthreads();
    for (int j = 0; j < DD; ++j) {
        float s = fc1b[j];
        for (int k = 0; k < DD; ++k) s += P[g][k] * fc1w[k * DD + j];
        Y1[g][j] = (s > 0.f) ? s : expm1f(s);
    }
    __syncthreads();
    float y2[CC];
    for (int c2 = 0; c2 < CC; ++c2) {
        float s = fc2b[c2];
        for (int j = 0; j < DD; ++j) s += Y1[g][j] * fc2w[j * CC + c2];
        y2[c2] = s;
    }
    for (int c2 = 0; c2 < CC; ++c2) {
        float m = y2[c2];
#pragma unroll
        for (int o = 32; o > 0; o >>= 1) m = fmaxf(m, __shfl_xor(m, o));
        float sexp = __expf(y2[c2] - m);
#pragma unroll
        for (int o = 32; o > 0; o >>= 1) sexp += __shfl_xor(sexp, o);
        out[g * CC + c2] = y2[c2] - m - logf(sexp);
    }
}

// ---------------- launcher ----------------
extern "C" void kernel_launch(void* const* d_in, const int* in_sizes, int n_in,
                              void* d_out, int out_size, void* d_ws, size_t ws_size,
                              hipStream_t stream) {
    const float* h    = (const float*)d_in[0];
    const int* src    = (const int*)d_in[1];
    const int* dst    = (const int*)d_in[2];
    const int* gid    = (const int*)d_in[3];
    const float* W0   = (const float*)d_in[4];
    const float* al0  = (const float*)d_in[5];
    const float* ar0  = (const float*)d_in[6];
    const float* W1   = (const float*)d_in[7];
    const float* al1  = (const float*)d_in[8];
    const float* ar1  = (const float*)d_in[9];
    const float* W2   = (const float*)d_in[10];
    const float* al2  = (const float*)d_in[11];
    const float* ar2  = (const float*)d_in[12];
    const float* W3   = (const float*)d_in[13];
    const float* al3  = (const float*)d_in[14];
    const float* ar3  = (const float*)d_in[15];
    const float* fc1w = (const float*)d_in[16];
    const float* fc1b = (const float*)d_in[17];
    const float* fc2w = (const float*)d_in[18];
    const float* fc2b = (const float*)d_in[19];
    const int E = in_sizes[1];

    char* wsb = (char*)d_ws;
    size_t off = 0;
    auto alloc = [&](size_t bytes) -> void* {
        void* p = wsb + off;
        off = (off + bytes + 255) & ~(size_t)255;
        return p;
    };
    ushort* zt      = (ushort*)alloc((size_t)NN * 256 * 2);  // z bf16, packed [v][d][h] (H=4) / [v][d] (H=1)
    ushort* Ahi     = (ushort*)alloc((size_t)NN * 256 * 2);
    ushort* Alo     = (ushort*)alloc((size_t)NN * 256 * 2);
    float*  bufA    = (float*)alloc((size_t)NN * DD * 4);
    float*  el      = (float*)alloc((size_t)NN * HH * 4);
    float*  er      = (float*)alloc((size_t)NN * HH * 4);
    int*    counts  = (int*)alloc((size_t)NN * 4);
    int*    row_ptr = (int*)alloc((size_t)(NN + 1) * 4);
    int*    fill    = (int*)alloc((size_t)NN * 4);
    int*    excl    = (int*)alloc((size_t)NN * 4);
    int*    bsum    = (int*)alloc((size_t)256 * 4);
    int*    col_src = (int*)alloc((size_t)E * 4);
    float*  pooled  = (float*)alloc((size_t)GG * DD * 4);
    float*  gcnt    = (float*)alloc((size_t)GG * 4);
    ushort* w0h     = (ushort*)alloc((size_t)IN_F * 256 * 2);
    ushort* w0l     = (ushort*)alloc((size_t)IN_F * 256 * 2);
    ushort* w1h     = (ushort*)alloc((size_t)256 * 256 * 2);
    ushort* w1l     = (ushort*)alloc((size_t)256 * 256 * 2);
    ushort* w2h     = (ushort*)alloc((size_t)256 * 256 * 2);
    ushort* w2l     = (ushort*)alloc((size_t)256 * 256 * 2);
    ushort* w3h     = (ushort*)alloc((size_t)256 * 64 * 2);
    ushort* w3l     = (ushort*)alloc((size_t)256 * 64 * 2);

    // ---- CSR build ----
    hipMemsetAsync(counts, 0, (size_t)NN * 4, stream);
    int eg = (E + 255) / 256;
    const int nScanBlk = (NN + 255) / 256;  // 196
    hist_kernel<<<eg, 256, 0, stream>>>(dst, E, counts);
    scan_blk<<<nScanBlk, 256, 0, stream>>>(counts, excl, bsum, NN);
    scan_top<<<1, 256, 0, stream>>>(bsum, nScanBlk);
    scan_fin<<<nScanBlk, 256, 0, stream>>>(excl, bsum, row_ptr, fill, NN, E);
    scatter_kernel<<<eg, 256, 0, stream>>>(src, dst, E, fill, col_src);

    // ---- weight + input conversions ----
    wconv_kernel<<<(IN_F * 256 + 255) / 256, 256, 0, stream>>>(W0, IN_F, 256, w0h, w0l);
    wconv_kernel<<<(256 * 256 + 255) / 256, 256, 0, stream>>>(W1, 256, 256, w1h, w1l);
    wconv_kernel<<<(256 * 256 + 255) / 256, 256, 0, stream>>>(W2, 256, 256, w2h, w2l);
    wconv_kernel<<<(256 * 64 + 255) / 256, 256, 0, stream>>>(W3, 256, 64, w3h, w3l);
    hconv_kernel<<<(NN * IN_F + 255) / 256, 256, 0, stream>>>(h, Ahi, Alo, NN * IN_F);

    const int gemmGrid = (NN + 63) / 64;  // 782
    const int waveBlocks = (NN + 3) / 4;  // 12500

    // ---- layer 0 (K=128, N=256, H=4) ----
    gemm_mfma_eler<256, 4><<<gemmGrid, 256, 0, stream>>>(Ahi, Alo, w0h, w0l, zt, al0, ar0, el, er, NN, IN_F);
    agg_fused<4, true><<<waveBlocks, 256, 0, stream>>>(zt, el, er, row_ptr, col_src, nullptr, Ahi, Alo);

    // ---- layer 1 ----
    gemm_mfma_eler<256, 4><<<gemmGrid, 256, 0, stream>>>(Ahi, Alo, w1h, w1l, zt, al1, ar1, el, er, NN, 256);
    agg_fused<4, true><<<waveBlocks, 256, 0, stream>>>(zt, el, er, row_ptr, col_src, nullptr, Ahi, Alo);

    // ---- layer 2 ----
    gemm_mfma_eler<256, 4><<<gemmGrid, 256, 0, stream>>>(Ahi, Alo, w2h, w2l, zt, al2, ar2, el, er, NN, 256);
    agg_fused<4, true><<<waveBlocks, 256, 0, stream>>>(zt, el, er, row_ptr, col_src, nullptr, Ahi, Alo);

    // ---- layer 3 (K=256, N=64, H=1) ----
    gemm_mfma_eler<64, 1><<<gemmGrid, 256, 0, stream>>>(Ahi, Alo, w3h, w3l, zt, al3, ar3, el, er, NN, 256);
    agg_fused<1, false><<<waveBlocks, 256, 0, stream>>>(zt, el, er, row_ptr, col_src, bufA, nullptr, nullptr);

    // ---- pooling + head ----
    pool_kernel<<<GG, 256, 0, stream>>>(bufA, gid, pooled, gcnt);
    head_kernel<<<1, 64, 0, stream>>>(pooled, gcnt, fc1w, fc1b, fc2w, fc2b, (float*)d_out);
}

// Round 8
// 627.148 us; speedup vs baseline: 2.3363x; 1.0899x over previous
//
#include <hip/hip_runtime.h>
#include <hip/hip_bf16.h>
#include <math.h>

#define NN 50000
#define IN_F 128
#define DD 64
#define HH 4
#define CC 10
#define GG 64
#define NEG_SLOPE 0.2f

typedef __attribute__((ext_vector_type(8))) short bf16x8;
typedef __attribute__((ext_vector_type(4))) float f32x4;
typedef __attribute__((ext_vector_type(4))) unsigned short u16x4;

__device__ inline ushort f2bf(float f) {
    unsigned u = __float_as_uint(f);
    unsigned r = (u + 0x7fffu + ((u >> 16) & 1u)) >> 16;
    return (ushort)r;
}
__device__ inline float bf2f(ushort b) { return __uint_as_float(((unsigned)b) << 16); }

// ---------------- wave helpers ----------------
__device__ inline float wave_max(float v) {
#pragma unroll
    for (int o = 32; o > 0; o >>= 1) v = fmaxf(v, __shfl_xor(v, o));
    return v;
}
__device__ inline float wave_sum(float v) {
#pragma unroll
    for (int o = 32; o > 0; o >>= 1) v += __shfl_xor(v, o);
    return v;
}

// ---------------- CSR build ----------------
__global__ void hist_kernel(const int* __restrict__ dst, int E, int* __restrict__ counts) {
    int i = blockIdx.x * blockDim.x + threadIdx.x;
    if (i < E) atomicAdd(&counts[dst[i]], 1);
}

__global__ __launch_bounds__(256) void scan_blk(const int* __restrict__ counts,
                                                int* __restrict__ excl,
                                                int* __restrict__ bsum, int n) {
    __shared__ int sh[256];
    int t = threadIdx.x;
    int i = blockIdx.x * 256 + t;
    int v = (i < n) ? counts[i] : 0;
    sh[t] = v;
    __syncthreads();
#pragma unroll
    for (int o = 1; o < 256; o <<= 1) {
        int u = (t >= o) ? sh[t - o] : 0;
        __syncthreads();
        sh[t] += u;
        __syncthreads();
    }
    if (i < n) excl[i] = sh[t] - v;
    if (t == 255) bsum[blockIdx.x] = sh[255];
}

__global__ __launch_bounds__(256) void scan_top(int* __restrict__ bsum, int nb) {
    __shared__ int sh[256];
    int t = threadIdx.x;
    int v = (t < nb) ? bsum[t] : 0;
    sh[t] = v;
    __syncthreads();
#pragma unroll
    for (int o = 1; o < 256; o <<= 1) {
        int u = (t >= o) ? sh[t - o] : 0;
        __syncthreads();
        sh[t] += u;
        __syncthreads();
    }
    if (t < nb) bsum[t] = sh[t] - v;  // exclusive
}

__global__ __launch_bounds__(256) void scan_fin(const int* __restrict__ excl,
                                                const int* __restrict__ bsum,
                                                int* __restrict__ row_ptr,
                                                int* __restrict__ fill, int n, int E) {
    int i = blockIdx.x * blockDim.x + threadIdx.x;
    if (i < n) {
        int r = excl[i] + bsum[i >> 8];
        row_ptr[i] = r;
        fill[i] = r;
    }
    if (i == 0) row_ptr[n] = E;
}

__global__ void scatter_kernel(const int* __restrict__ src, const int* __restrict__ dst,
                               int E, int* __restrict__ fill, int* __restrict__ col_src) {
    int i = blockIdx.x * blockDim.x + threadIdx.x;
    if (i < E) {
        int p = atomicAdd(&fill[dst[i]], 1);
        col_src[p] = src[i];
    }
}

// ---------------- W -> transposed, k-blocked, bf16: Wt[kb][n][kk] ----------------
__global__ void wconv_kernel(const float* __restrict__ W, int K, int N,
                             ushort* __restrict__ thi) {
    int i = blockIdx.x * blockDim.x + threadIdx.x;
    if (i >= K * N) return;
    int k = i / N, n = i - k * N;
    size_t o = ((size_t)(k >> 5) * N + n) * 32 + (k & 31);
    thi[o] = f2bf(W[i]);
}

// ---------------- MFMA GEMM (2-term bf16 split A, bf16 W) + fused el/er ----------------
// A: AF32 ? fp32 [M][K] (split in-register) : pre-split hi/lo bf16 [M][K].
// W: blocked [K/32][N][32] bf16. z out bf16: H=4 packed [r][d][h]; H=1 [r][d].
template <int N, int H, bool AF32>
__global__ __launch_bounds__(256) void gemm_mfma_eler(
    const void* __restrict__ A0, const ushort* __restrict__ Alo,
    const ushort* __restrict__ Wthi,
    ushort* __restrict__ zt, const float* __restrict__ al, const float* __restrict__ ar,
    float* __restrict__ el, float* __restrict__ er, int M, int K) {
    constexpr int NT = N / 16;
    __shared__ ushort Bh[N][34];  // 68B row stride (odd bank count) -> near-uniform spread
    const int t = threadIdx.x;
    const int w = t >> 6, lane = t & 63;
    const int cl = lane & 15, g = lane >> 4;
    const int bm = blockIdx.x * 64;
    const int arow = bm + 16 * w + cl;
    const bool aval = arow < M;
    const size_t abase = (size_t)arow * K;
    const float* Af = (const float*)A0;
    const ushort* Ahi = (const ushort*)A0;

    f32x4 acc[NT];
#pragma unroll
    for (int nt = 0; nt < NT; ++nt) acc[nt] = (f32x4){0.f, 0.f, 0.f, 0.f};

    const int nkb = K >> 5;
    for (int kb = 0; kb < nkb; ++kb) {
        __syncthreads();
        if (t < N) {
            const float4* gsh = (const float4*)(Wthi + ((size_t)kb * N + t) * 32);
#pragma unroll
            for (int q = 0; q < 4; ++q) *(float4*)&Bh[t][q * 8] = gsh[q];
        }
        __syncthreads();
        bf16x8 a_hi = {0, 0, 0, 0, 0, 0, 0, 0};
        bf16x8 a_lo = {0, 0, 0, 0, 0, 0, 0, 0};
        if (aval) {
            if (AF32) {
                float4 f0 = *(const float4*)(Af + abase + kb * 32 + g * 8);
                float4 f1 = *(const float4*)(Af + abase + kb * 32 + g * 8 + 4);
                float fv[8] = {f0.x, f0.y, f0.z, f0.w, f1.x, f1.y, f1.z, f1.w};
#pragma unroll
                for (int q = 0; q < 8; ++q) {
                    ushort hb = f2bf(fv[q]);
                    a_hi[q] = (short)hb;
                    a_lo[q] = (short)f2bf(fv[q] - bf2f(hb));
                }
            } else {
                a_hi = *(const bf16x8*)(Ahi + abase + kb * 32 + g * 8);
                a_lo = *(const bf16x8*)(Alo + abase + kb * 32 + g * 8);
            }
        }
#pragma unroll
        for (int nt = 0; nt < NT; ++nt) {
            bf16x8 b_hi = *(const bf16x8*)&Bh[16 * nt + cl][g * 8];
            acc[nt] = __builtin_amdgcn_mfma_f32_16x16x32_bf16(a_hi, b_hi, acc[nt], 0, 0, 0);
            acc[nt] = __builtin_amdgcn_mfma_f32_16x16x32_bf16(a_lo, b_hi, acc[nt], 0, 0, 0);
        }
    }

    // z store (bf16). Lane holds C[r0+j][16nt+cl], r0 = bm+16w+4g.
    const int r0 = bm + 16 * w + 4 * g;
    if (H == 4) {
#pragma unroll
        for (int tt = 0; tt < 4; ++tt) {
#pragma unroll
            for (int j = 0; j < 4; ++j) {
                int r = r0 + j;
                if (r < M) {
                    u16x4 pv;
#pragma unroll
                    for (int h = 0; h < 4; ++h) pv[h] = f2bf(acc[4 * h + tt][j]);
                    *(u16x4*)&zt[(size_t)r * 256 + (16 * tt + cl) * 4] = pv;
                }
            }
        }
    } else {
#pragma unroll
        for (int nt = 0; nt < NT; ++nt) {
#pragma unroll
            for (int j = 0; j < 4; ++j) {
                int r = r0 + j;
                if (r < M) zt[(size_t)r * N + 16 * nt + cl] = f2bf(acc[nt][j]);
            }
        }
    }
    // fused el/er
#pragma unroll
    for (int h = 0; h < H; ++h) {
        float pl[4] = {0.f, 0.f, 0.f, 0.f};
        float pr[4] = {0.f, 0.f, 0.f, 0.f};
#pragma unroll
        for (int tt = 0; tt < 4; ++tt) {
            int nt = 4 * h + tt;
            float av = al[h * DD + 16 * tt + cl];
            float rv = ar[h * DD + 16 * tt + cl];
#pragma unroll
            for (int j = 0; j < 4; ++j) {
                pl[j] += acc[nt][j] * av;
                pr[j] += acc[nt][j] * rv;
            }
        }
#pragma unroll
        for (int j = 0; j < 4; ++j) {
#pragma unroll
            for (int o = 1; o < 16; o <<= 1) {
                pl[j] += __shfl_xor(pl[j], o);
                pr[j] += __shfl_xor(pr[j], o);
            }
        }
        if (cl == 0) {
#pragma unroll
            for (int j = 0; j < 4; ++j) {
                int r = r0 + j;
                if (r < M) {
                    el[(size_t)r * H + h] = pl[j];
                    er[(size_t)r * H + h] = pr[j];
                }
            }
        }
    }
}

// ---------------- fused attention + aggregation: one wave per dst ----------------
// phase A (lane=edge): alpha computed once per edge -> per-wave LDS
// phase B (lane=feature): acc[h] += alpha[j][h] * z[src_j]  (LDS broadcast reads)
template <int H, bool SPLIT>
__global__ __launch_bounds__(256) void agg_fused(const ushort* __restrict__ zt,
                                                 const float* __restrict__ el,
                                                 const float* __restrict__ er,
                                                 const int* __restrict__ row_ptr,
                                                 const int* __restrict__ col_src,
                                                 float* __restrict__ outf,
                                                 ushort* __restrict__ ohi,
                                                 ushort* __restrict__ olo) {
    __shared__ float alf[4][64][H];  // per-wave alpha slab
    __shared__ int als[4][64];       // per-wave src ids
    const int wid = threadIdx.x >> 6;
    const int lane = threadIdx.x & 63;
    int v = blockIdx.x * 4 + wid;
    if (v >= NN) return;
    int start = row_ptr[v], end = row_ptr[v + 1];
    int deg = end - start;
    float erd[H], acc[H];
#pragma unroll
    for (int h = 0; h < H; ++h) {
        erd[h] = er[(size_t)v * H + h];
        acc[h] = 0.f;
    }

    auto agg_chunk = [&](int cnt) {
        int j = 0;
        for (; j + 4 <= cnt; j += 4) {
            int s0 = als[wid][j + 0], s1 = als[wid][j + 1];
            int s2 = als[wid][j + 2], s3 = als[wid][j + 3];
            if (H == 4) {
                f32x4 a0 = *(const f32x4*)&alf[wid][j + 0][0];
                f32x4 a1 = *(const f32x4*)&alf[wid][j + 1][0];
                f32x4 a2 = *(const f32x4*)&alf[wid][j + 2][0];
                f32x4 a3 = *(const f32x4*)&alf[wid][j + 3][0];
                u16x4 z0 = *(const u16x4*)&zt[(size_t)s0 * 256 + lane * 4];
                u16x4 z1 = *(const u16x4*)&zt[(size_t)s1 * 256 + lane * 4];
                u16x4 z2 = *(const u16x4*)&zt[(size_t)s2 * 256 + lane * 4];
                u16x4 z3 = *(const u16x4*)&zt[(size_t)s3 * 256 + lane * 4];
#pragma unroll
                for (int h = 0; h < 4; ++h) {
                    acc[h] += a0[h] * bf2f(z0[h]);
                    acc[h] += a1[h] * bf2f(z1[h]);
                    acc[h] += a2[h] * bf2f(z2[h]);
                    acc[h] += a3[h] * bf2f(z3[h]);
                }
            } else {
                float a0 = alf[wid][j + 0][0], a1 = alf[wid][j + 1][0];
                float a2 = alf[wid][j + 2][0], a3 = alf[wid][j + 3][0];
                ushort z0 = zt[(size_t)s0 * 64 + lane];
                ushort z1 = zt[(size_t)s1 * 64 + lane];
                ushort z2 = zt[(size_t)s2 * 64 + lane];
                ushort z3 = zt[(size_t)s3 * 64 + lane];
                acc[0] += a0 * bf2f(z0);
                acc[0] += a1 * bf2f(z1);
                acc[0] += a2 * bf2f(z2);
                acc[0] += a3 * bf2f(z3);
            }
        }
        for (; j < cnt; ++j) {
            int s = als[wid][j];
            if (H == 4) {
                f32x4 a = *(const f32x4*)&alf[wid][j][0];
                u16x4 z = *(const u16x4*)&zt[(size_t)s * 256 + lane * 4];
#pragma unroll
                for (int h = 0; h < 4; ++h) acc[h] += a[h] * bf2f(z[h]);
            } else {
                acc[0] += alf[wid][j][0] * bf2f(zt[(size_t)s * 64 + lane]);
            }
        }
    };

    if (deg <= 64) {
        bool valid = lane < deg;
        int s = col_src[valid ? start + lane : start];
        als[wid][lane] = s;
        float e[H];
        if (H == 4) {
            f32x4 ev = *(const f32x4*)&el[(size_t)s * 4];
#pragma unroll
            for (int h = 0; h < 4; ++h) {
                float x = ev[h] + erd[h];
                x = (x >= 0.f) ? x : NEG_SLOPE * x;
                e[h] = valid ? x : -1e30f;
            }
        } else {
            float x = el[s] + erd[0];
            x = (x >= 0.f) ? x : NEG_SLOPE * x;
            e[0] = valid ? x : -1e30f;
        }
#pragma unroll
        for (int h = 0; h < H; ++h) {
            float m = wave_max(e[h]);
            float ex = valid ? __expf(e[h] - m) : 0.f;
            float den = wave_sum(ex);
            alf[wid][lane][h] = ex * (1.f / den);
        }
        __builtin_amdgcn_wave_barrier();
        agg_chunk(deg);
    } else {
        float m[H];
#pragma unroll
        for (int h = 0; h < H; ++h) m[h] = -1e30f;
        for (int base = start; base < end; base += 64) {
            int i = base + lane;
            bool valid = i < end;
            int s = col_src[valid ? i : start];
#pragma unroll
            for (int h = 0; h < H; ++h) {
                float x = el[(size_t)s * H + h] + erd[h];
                x = (x >= 0.f) ? x : NEG_SLOPE * x;
                m[h] = fmaxf(m[h], valid ? x : -1e30f);
            }
        }
        float den[H];
#pragma unroll
        for (int h = 0; h < H; ++h) {
            m[h] = wave_max(m[h]);
            den[h] = 0.f;
        }
        for (int base = start; base < end; base += 64) {
            int i = base + lane;
            bool valid = i < end;
            int s = col_src[valid ? i : start];
#pragma unroll
            for (int h = 0; h < H; ++h) {
                float x = el[(size_t)s * H + h] + erd[h];
                x = (x >= 0.f) ? x : NEG_SLOPE * x;
                den[h] += valid ? __expf(x - m[h]) : 0.f;
            }
        }
        float inv[H];
#pragma unroll
        for (int h = 0; h < H; ++h) inv[h] = 1.f / wave_sum(den[h]);
        for (int base = start; base < end; base += 64) {
            int i = base + lane;
            bool valid = i < end;
            int s = col_src[valid ? i : start];
            als[wid][lane] = s;
#pragma unroll
            for (int h = 0; h < H; ++h) {
                float x = el[(size_t)s * H + h] + erd[h];
                x = (x >= 0.f) ? x : NEG_SLOPE * x;
                alf[wid][lane][h] = valid ? __expf(x - m[h]) * inv[h] : 0.f;
            }
            __builtin_amdgcn_wave_barrier();
            int cnt = min(64, end - base);
            agg_chunk(cnt);
            __builtin_amdgcn_wave_barrier();
        }
    }

#pragma unroll
    for (int h = 0; h < H; ++h) {
        float r = acc[h];
        r = (r > 0.f) ? r : 0.f;  // fused ReLU
        size_t idx = (size_t)v * H * DD + h * DD + lane;
        if (SPLIT) {
            ushort hb = f2bf(r);
            ohi[idx] = hb;
            olo[idx] = f2bf(r - bf2f(hb));
        } else {
            outf[idx] = r;
        }
    }
}

// ---------------- pooling ----------------
__device__ inline int lower_bound_dev(const int* a, int n, int v) {
    int lo = 0, hi = n;
    while (lo < hi) {
        int mid = (lo + hi) >> 1;
        if (a[mid] < v) lo = mid + 1; else hi = mid;
    }
    return lo;
}

__global__ __launch_bounds__(256) void pool_kernel(const float* __restrict__ x,
                                                   const int* __restrict__ gid,
                                                   float* __restrict__ pooled,
                                                   float* __restrict__ gcnt) {
    int g = blockIdx.x;
    int start = lower_bound_dev(gid, NN, g);
    int end = lower_bound_dev(gid, NN, g + 1);
    int lane = threadIdx.x & 63;
    int w = threadIdx.x >> 6;
    float acc = 0.f;
    for (int i = start + w; i < end; i += 4) acc += x[(size_t)i * DD + lane];
    __shared__ float red[4][DD];
    red[w][lane] = acc;
    __syncthreads();
    if (w == 0) {
        float s = red[0][lane] + red[1][lane] + red[2][lane] + red[3][lane];
        pooled[g * DD + lane] = s;
        if (lane == 0) gcnt[g] = (float)(end - start);
    }
}

// ---------------- head ----------------
__global__ __launch_bounds__(64) void head_kernel(const float* __restrict__ pooled,
                                                  const float* __restrict__ gcnt,
                                                  const float* __restrict__ fc1w,
                                                  const float* __restrict__ fc1b,
                                                  const float* __restrict__ fc2w,
                                                  const float* __restrict__ fc2b,
                                                  float* __restrict__ out) {
    __shared__ float P[GG][DD + 1];
    __shared__ float Y1[GG][DD + 1];
    int g = threadIdx.x;
    float c = fmaxf(gcnt[g], 1.0f);
    for (int k = 0; k < DD; ++k) P[g][k] = pooled[g * DD + k] / c;
    __syncthreads();
    for (int j = 0; j < DD; ++j) {
        float s = fc1b[j];
        for (int k = 0; k < DD; ++k) s += P[g][k] * fc1w[k * DD + j];
        Y1[g][j] = (s > 0.f) ? s : expm1f(s);
    }
    __syncthreads();
    float y2[CC];
    for (int c2 = 0; c2 < CC; ++c2) {
        float s = fc2b[c2];
        for (int j = 0; j < DD; ++j) s += Y1[g][j] * fc2w[j * CC + c2];
        y2[c2] = s;
    }
    for (int c2 = 0; c2 < CC; ++c2) {
        float m = y2[c2];
#pragma unroll
        for (int o = 32; o > 0; o >>= 1) m = fmaxf(m, __shfl_xor(m, o));
        float sexp = __expf(y2[c2] - m);
#pragma unroll
        for (int o = 32; o > 0; o >>= 1) sexp += __shfl_xor(sexp, o);
        out[g * CC + c2] = y2[c2] - m - logf(sexp);
    }
}

// ---------------- launcher ----------------
extern "C" void kernel_launch(void* const* d_in, const int* in_sizes, int n_in,
                              void* d_out, int out_size, void* d_ws, size_t ws_size,
                              hipStream_t stream) {
    const float* h    = (const float*)d_in[0];
    const int* src    = (const int*)d_in[1];
    const int* dst    = (const int*)d_in[2];
    const int* gid    = (const int*)d_in[3];
    const float* W0   = (const float*)d_in[4];
    const float* al0  = (const float*)d_in[5];
    const float* ar0  = (const float*)d_in[6];
    const float* W1   = (const float*)d_in[7];
    const float* al1  = (const float*)d_in[8];
    const float* ar1  = (const float*)d_in[9];
    const float* W2   = (const float*)d_in[10];
    const float* al2  = (const float*)d_in[11];
    const float* ar2  = (const float*)d_in[12];
    const float* W3   = (const float*)d_in[13];
    const float* al3  = (const float*)d_in[14];
    const float* ar3  = (const float*)d_in[15];
    const float* fc1w = (const float*)d_in[16];
    const float* fc1b = (const float*)d_in[17];
    const float* fc2w = (const float*)d_in[18];
    const float* fc2b = (const float*)d_in[19];
    const int E = in_sizes[1];

    char* wsb = (char*)d_ws;
    size_t off = 0;
    auto alloc = [&](size_t bytes) -> void* {
        void* p = wsb + off;
        off = (off + bytes + 255) & ~(size_t)255;
        return p;
    };
    ushort* zt      = (ushort*)alloc((size_t)NN * 256 * 2);  // z bf16, packed [v][d][h] (H=4) / [v][d] (H=1)
    ushort* Ahi     = (ushort*)alloc((size_t)NN * 256 * 2);
    ushort* Alo     = (ushort*)alloc((size_t)NN * 256 * 2);
    float*  bufA    = (float*)alloc((size_t)NN * DD * 4);
    float*  el      = (float*)alloc((size_t)NN * HH * 4);
    float*  er      = (float*)alloc((size_t)NN * HH * 4);
    int*    counts  = (int*)alloc((size_t)NN * 4);
    int*    row_ptr = (int*)alloc((size_t)(NN + 1) * 4);
    int*    fill    = (int*)alloc((size_t)NN * 4);
    int*    excl    = (int*)alloc((size_t)NN * 4);
    int*    bsum    = (int*)alloc((size_t)256 * 4);
    int*    col_src = (int*)alloc((size_t)E * 4);
    float*  pooled  = (float*)alloc((size_t)GG * DD * 4);
    float*  gcnt    = (float*)alloc((size_t)GG * 4);
    ushort* w0h     = (ushort*)alloc((size_t)IN_F * 256 * 2);
    ushort* w1h     = (ushort*)alloc((size_t)256 * 256 * 2);
    ushort* w2h     = (ushort*)alloc((size_t)256 * 256 * 2);
    ushort* w3h     = (ushort*)alloc((size_t)256 * 64 * 2);

    // ---- CSR build ----
    hipMemsetAsync(counts, 0, (size_t)NN * 4, stream);
    int eg = (E + 255) / 256;
    const int nScanBlk = (NN + 255) / 256;  // 196
    hist_kernel<<<eg, 256, 0, stream>>>(dst, E, counts);
    scan_blk<<<nScanBlk, 256, 0, stream>>>(counts, excl, bsum, NN);
    scan_top<<<1, 256, 0, stream>>>(bsum, nScanBlk);
    scan_fin<<<nScanBlk, 256, 0, stream>>>(excl, bsum, row_ptr, fill, NN, E);
    scatter_kernel<<<eg, 256, 0, stream>>>(src, dst, E, fill, col_src);

    // ---- weight conversions (bf16, transposed k-blocked) ----
    wconv_kernel<<<(IN_F * 256 + 255) / 256, 256, 0, stream>>>(W0, IN_F, 256, w0h);
    wconv_kernel<<<(256 * 256 + 255) / 256, 256, 0, stream>>>(W1, 256, 256, w1h);
    wconv_kernel<<<(256 * 256 + 255) / 256, 256, 0, stream>>>(W2, 256, 256, w2h);
    wconv_kernel<<<(256 * 64 + 255) / 256, 256, 0, stream>>>(W3, 256, 64, w3h);

    const int gemmGrid = (NN + 63) / 64;  // 782
    const int waveBlocks = (NN + 3) / 4;  // 12500

    // ---- layer 0 (K=128, N=256, H=4): A = h fp32, split in-register ----
    gemm_mfma_eler<256, 4, true><<<gemmGrid, 256, 0, stream>>>(h, nullptr, w0h, zt, al0, ar0, el, er, NN, IN_F);
    agg_fused<4, true><<<waveBlocks, 256, 0, stream>>>(zt, el, er, row_ptr, col_src, nullptr, Ahi, Alo);

    // ---- layer 1 ----
    gemm_mfma_eler<256, 4, false><<<gemmGrid, 256, 0, stream>>>(Ahi, Alo, w1h, zt, al1, ar1, el, er, NN, 256);
    agg_fused<4, true><<<waveBlocks, 256, 0, stream>>>(zt, el, er, row_ptr, col_src, nullptr, Ahi, Alo);

    // ---- layer 2 ----
    gemm_mfma_eler<256, 4, false><<<gemmGrid, 256, 0, stream>>>(Ahi, Alo, w2h, zt, al2, ar2, el, er, NN, 256);
    agg_fused<4, true><<<waveBlocks, 256, 0, stream>>>(zt, el, er, row_ptr, col_src, nullptr, Ahi, Alo);

    // ---- layer 3 (K=256, N=64, H=1) ----
    gemm_mfma_eler<64, 1, false><<<gemmGrid, 256, 0, stream>>>(Ahi, Alo, w3h, zt, al3, ar3, el, er, NN, 256);
    agg_fused<1, false><<<waveBlocks, 256, 0, stream>>>(zt, el, er, row_ptr, col_src, bufA, nullptr, nullptr);

    // ---- pooling + head ----
    pool_kernel<<<GG, 256, 0, stream>>>(bufA, gid, pooled, gcnt);
    head_kernel<<<1, 64, 0, stream>>>(pooled, gcnt, fc1w, fc1b, fc2w, fc2b, (float*)d_out);
}